// Round 8
// baseline (238.462 us; speedup 1.0000x reference)
//
#include <hip/hip_runtime.h>
#include <hip/hip_fp16.h>

// DeformConv2d: B=16, Cin=64, Cout=64, H=W=64, K=3, stride=1, pad=1, dil=1
// Round 8:
//  Kernel B: geometry records preloaded to REGISTERS (9/thread, full k-loop
//    unroll -> constant indices), no weight LDS (afrag = coalesced global
//    load from pre-transposed w2t), double-buffered colsT, 1 barrier/iter.
//  Kernel A: offset conv as MFMA GEMM (M=18->32, K=576, N=64px), regular-
//    conv cols staged coalesced, weights pre-transposed woff2t.

#define HDIM 64
#define WDIM 64
#define KOFF 18
#define CPAD 40          // padded k-stride (halfs): 80B rows, 16B-aligned
#define PXB 32           // pixels per block (kernel B)
#define GSTR 33          // fallback-only LDS geometry stride

// ws layout
#define W2T_BYTES    (18 * 64 * 32 * 2)               // 73728  [kg][64co][32k]
#define WOFF2T_OFF   (W2T_BYTES)
#define WOFF2T_BYTES (18 * 32 * 32 * 2)               // 36864  [kg][32co][32k]
#define GREC_OFF     (WOFF2T_OFF + WOFF2T_BYTES)      // 110592 (16B aligned)
#define GREC_BYTES   (16 * 64 * 9 * 64 * 16)          // 9437184
#define WS_NEED      (GREC_OFF + GREC_BYTES)

typedef _Float16 half8 __attribute__((ext_vector_type(8)));
typedef _Float16 half4 __attribute__((ext_vector_type(4)));
typedef float floatx4 __attribute__((ext_vector_type(4)));

// ---------------------------------------------------------------------------
// transpose weights: w2t[(kg*64+co)*32+kl] = w_dcn[co*576+kg*32+kl]
//                    woff2t[(kg*32+co)*32+kl] = co<18 ? w_off[co*576+kg*32+kl] : 0
__global__ void cvt_w(const float* __restrict__ w_dcn,
                      const float* __restrict__ w_off,
                      _Float16* __restrict__ w2t,
                      _Float16* __restrict__ woff2t) {
    int e = blockIdx.x * 256 + threadIdx.x;
    if (e < 18 * 64 * 32) {
        int kl = e & 31, co = (e >> 5) & 63, kg = e >> 11;
        w2t[e] = (_Float16)w_dcn[co * 576 + kg * 32 + kl];
    } else {
        int e2 = e - 18 * 64 * 32;
        if (e2 < 18 * 32 * 32) {
            int kl = e2 & 31, co = (e2 >> 5) & 31, kg = e2 >> 10;
            woff2t[e2] = (co < KOFF) ? (_Float16)w_off[co * 576 + kg * 32 + kl]
                                     : (_Float16)0.f;
        }
    }
}

// ---------------------------------------------------------------------------
// Kernel A: offset conv via MFMA (M=32 padded, K=576, N=64px) + geometry.
// One block per (b, ho) row.
__launch_bounds__(256)
__global__ void dcn_offsets(const float* __restrict__ x,
                            const _Float16* __restrict__ woff2t,
                            const float* __restrict__ b_off,
                            uint4* __restrict__ grecs) {
    const int bx = blockIdx.x;       // 0..1023
    const int b  = bx >> 6;
    const int ho = bx & 63;
    const int t  = threadIdx.x;
    const int lane = t & 63;
    const int wid  = t >> 6;

    __shared__ __align__(16) _Float16 colsA[64 * CPAD];   // 5120 B
    __shared__ __align__(16) float offlds[KOFF * 64];     // 4608 B

    const float* xb = x + (size_t)b * 64 * (HDIM * WDIM);
    const int px = t & 63;           // staging: pixel
    const int gs = t >> 6;           // staging: k-octet 0..3
    const int r  = lane & 15;
    const int q  = lane >> 4;

    floatx4 am0 = {0.f, 0.f, 0.f, 0.f};
    floatx4 am1 = {0.f, 0.f, 0.f, 0.f};

#pragma unroll
    for (int kg = 0; kg < 18; ++kg) {
        // stage regular-conv cols [64px][32k] (coalesced over px)
        half8 hv;
#pragma unroll
        for (int j = 0; j < 8; ++j) {
            int k   = kg * 32 + gs * 8 + j;
            int cin = k / 9;
            int tap = k - cin * 9;
            int dy  = tap / 3, dxk = tap - dy * 3;
            int y   = ho + dy - 1;
            int xc  = px + dxk - 1;
            bool ok = ((unsigned)y < (unsigned)HDIM) && ((unsigned)xc < (unsigned)WDIM);
            float v = ok ? xb[(size_t)cin * 4096 + y * WDIM + xc] : 0.f;
            hv[j] = (_Float16)v;
        }
        *(half8*)&colsA[px * CPAD + gs * 8] = hv;
        __syncthreads();

        half8 bfr = *(const half8*)&colsA[(wid * 16 + r) * CPAD + q * 8];
        half8 a0  = *(const half8*)&woff2t[((kg * 32 + r) * 32) + q * 8];
        half8 a1  = *(const half8*)&woff2t[((kg * 32 + 16 + r) * 32) + q * 8];
        am0 = __builtin_amdgcn_mfma_f32_16x16x32_f16(a0, bfr, am0, 0, 0, 0);
        am1 = __builtin_amdgcn_mfma_f32_16x16x32_f16(a1, bfr, am1, 0, 0, 0);
        __syncthreads();
    }

    // write offsets: D[m=co][n=px], col=lane&15 -> px tile, row=q*4+reg -> co
    {
        int pxg = wid * 16 + r;
#pragma unroll
        for (int reg = 0; reg < 4; ++reg) {
            int co = q * 4 + reg;                 // 0..15
            offlds[co * 64 + pxg] = am0[reg] + b_off[co];
            int co2 = 16 + q * 4 + reg;           // 16..31
            if (co2 < KOFF)
                offlds[co2 * 64 + pxg] = am1[reg] + b_off[co2];
        }
    }
    __syncthreads();

    // geometry records: 9 taps x 64 px -> 16B each
    for (int e = t; e < 9 * 64; e += 256) {
        int tap = e >> 6;
        int px2 = e & 63;
        float offy = offlds[(2 * tap) * 64 + px2];
        float offx = offlds[(2 * tap + 1) * 64 + px2];
        float py  = offy + (float)(tap / 3) + (float)(ho - 1);
        float pxf = offx + (float)(tap % 3) + (float)(px2 - 1);
        float fy = floorf(py), fx = floorf(pxf);
        int y0 = (int)fy, x0 = (int)fx;
        float wy1 = py - fy, wx1 = pxf - fx;
        float wy0 = 1.f - wy1, wx0 = 1.f - wx1;
        bool y0ok = ((unsigned)y0 < (unsigned)HDIM);
        bool x0ok = ((unsigned)x0 < (unsigned)WDIM);
        bool y1ok = ((unsigned)(y0 + 1) < (unsigned)HDIM);
        bool x1ok = ((unsigned)(x0 + 1) < (unsigned)WDIM);
        float w00 = (y0ok && x0ok) ? wy0 * wx0 : 0.f;
        float w01 = (y0ok && x1ok) ? wy0 * wx1 : 0.f;
        float w10 = (y1ok && x0ok) ? wy1 * wx0 : 0.f;
        float w11 = (y1ok && x1ok) ? wy1 * wx1 : 0.f;
        int yc0 = min(max(y0, 0), HDIM - 1);
        int xc0 = min(max(x0, 0), WDIM - 1);
        int yc1 = min(max(y0 + 1, 0), HDIM - 1);
        int xc1 = min(max(x0 + 1, 0), WDIM - 1);
        union { __half2 h; unsigned u; } c0, c1;
        c0.h = __floats2half2_rn(w00, w01);
        c1.h = __floats2half2_rn(w10, w11);
        uint4 rec;
        rec.x = (unsigned)(yc0 * WDIM + xc0) | ((unsigned)(xc1 - xc0) << 12)
              | ((unsigned)(yc1 - yc0) << 13);
        rec.y = c0.u;
        rec.z = c1.u;
        rec.w = 0u;
        grecs[((size_t)(b * 64 + ho) * 9 + tap) * 64 + px2] = rec;
    }
}

// ---------------------------------------------------------------------------
// Kernel B: gather + MFMA, records in registers, dbuf colsT, no weight LDS.
__launch_bounds__(256)
__global__ void dcn_gemm(const float* __restrict__ x,
                         const _Float16* __restrict__ w2t,
                         const uint4* __restrict__ grecs,
                         const float* __restrict__ b_dcn,
                         float* __restrict__ out) {
    const int bx   = blockIdx.x;        // 0..2047
    const int b    = bx >> 7;
    const int ho   = (bx >> 1) & 63;
    const int half = bx & 1;
    const int t    = threadIdx.x;
    const int lane = t & 63;
    const int wid  = t >> 6;

    __shared__ __align__(16) _Float16 colsT[2][PXB * CPAD];  // 2x2560 B

    const float* xb = x + (size_t)b * 64 * (HDIM * WDIM);
    const int px = t & 31;              // gather pixel (lane-consecutive)
    const int gi = t >> 5;              // gather k-quad group 0..7
    const int r  = lane & 15;
    const int q  = lane >> 4;

    // preload this pixel's 9 geometry records into registers
    unsigned rmeta[9], rw0[9], rw1[9];
    {
        const uint4* gp = grecs + ((size_t)(b * 64 + ho) * 9) * 64 + half * PXB + px;
#pragma unroll
        for (int tap = 0; tap < 9; ++tap) {
            uint4 rr = gp[tap * 64];
            rmeta[tap] = rr.x; rw0[tap] = rr.y; rw1[tap] = rr.z;
        }
    }

    floatx4 acc0 = {0.f, 0.f, 0.f, 0.f};
    floatx4 acc1 = {0.f, 0.f, 0.f, 0.f};

    auto gather = [&](int i) {
        half4 vb;
#pragma unroll
        for (int j = 0; j < 4; ++j) {
            int k   = i * 32 + gi * 4 + j;
            int cin = k / 9;
            int tap = k - cin * 9;
            const float* xc = xb + (size_t)cin * 4096;
            unsigned m = rmeta[tap];
            unsigned base = m & 0xfffu;
            unsigned dx   = (m >> 12) & 1u;
            unsigned dy64 = (m >> 7) & 64u;
            union { unsigned u; __half2 h; } c0, c1;
            c0.u = rw0[tap]; c1.u = rw1[tap];
            float v00 = xc[base];
            float v01 = xc[base + dx];
            float v10 = xc[base + dy64];
            float v11 = xc[base + dy64 + dx];
            float v = v00 * (float)c0.h.x + v01 * (float)c0.h.y
                    + v10 * (float)c1.h.x + v11 * (float)c1.h.y;
            vb[j] = (_Float16)v;
        }
        *(half4*)&colsT[i & 1][px * CPAD + gi * 4] = vb;
    };

    half8 af = *(const half8*)&w2t[(size_t)(wid * 16 + r) * 32 + q * 8];
    gather(0);
    __syncthreads();

#pragma unroll
    for (int i = 1; i < 18; ++i) {
        half8 afn = *(const half8*)&w2t[((size_t)i * 2048 + (wid * 16 + r) * 32) + q * 8];
        gather(i);
        half8 b0 = *(const half8*)&colsT[(i - 1) & 1][r * CPAD + q * 8];
        half8 b1 = *(const half8*)&colsT[(i - 1) & 1][(16 + r) * CPAD + q * 8];
        acc0 = __builtin_amdgcn_mfma_f32_16x16x32_f16(af, b0, acc0, 0, 0, 0);
        acc1 = __builtin_amdgcn_mfma_f32_16x16x32_f16(af, b1, acc1, 0, 0, 0);
        af = afn;
        __syncthreads();
    }
    {
        half8 b0 = *(const half8*)&colsT[1][r * CPAD + q * 8];
        half8 b1 = *(const half8*)&colsT[1][(16 + r) * CPAD + q * 8];
        acc0 = __builtin_amdgcn_mfma_f32_16x16x32_f16(af, b0, acc0, 0, 0, 0);
        acc1 = __builtin_amdgcn_mfma_f32_16x16x32_f16(af, b1, acc1, 0, 0, 0);
    }

    const int r0 = q * 4;
#pragma unroll
    for (int reg = 0; reg < 4; ++reg) {
        int co = wid * 16 + r0 + reg;
        float bias = b_dcn[co];
        size_t o = (((size_t)b * 64 + co) * HDIM + ho) * WDIM + half * PXB;
        out[o + r]      = acc0[reg] + bias;
        out[o + 16 + r] = acc1[reg] + bias;
    }
}

// ---------------------------------------------------------------------------
// Fused fallback (R7 path) used only when ws is too small.
__launch_bounds__(256, 4)
__global__ void dcn_fused(const float* __restrict__ x,
                          const float* __restrict__ w_off,
                          const float* __restrict__ b_off,
                          const float* __restrict__ w_dcn,
                          const float* __restrict__ b_dcn,
                          float* __restrict__ out) {
    const int bx   = blockIdx.x;
    const int b    = bx >> 7;
    const int ho   = (bx >> 1) & 63;
    const int half = bx & 1;
    const int t    = threadIdx.x;
    const int lane = t & 63;
    const int wid  = t >> 6;

    __shared__ __align__(16) float    offlds[KOFF * PXB];
    __shared__ __align__(16) uint4    grec[9 * GSTR];
    __shared__ __align__(16) _Float16 colsT[PXB * CPAD];
    __shared__ __align__(16) _Float16 wlds[64 * CPAD];

    const float* xb = x + (size_t)b * 64 * (HDIM * WDIM);

    {
        const int px = t >> 3;
        const int c8 = t & 7;
        const int gx = half * PXB + px;
        const int cb = c8 * 8;
        float acc[KOFF];
#pragma unroll
        for (int i = 0; i < KOFF; ++i) acc[i] = 0.f;
        for (int ci = 0; ci < 8; ++ci) {
            const float* xc = xb + (size_t)(cb + ci) * (HDIM * WDIM);
#pragma unroll
            for (int ky = 0; ky < 3; ++ky) {
                int y = ho + ky - 1;
                bool yok = ((unsigned)y < (unsigned)HDIM);
#pragma unroll
                for (int kx = 0; kx < 3; ++kx) {
                    int xcol = gx + kx - 1;
                    bool ok = yok && ((unsigned)xcol < (unsigned)WDIM);
                    float xv = ok ? xc[y * WDIM + xcol] : 0.f;
#pragma unroll
                    for (int co = 0; co < KOFF; ++co)
                        acc[co] += xv * w_off[co * 576 + (cb + ci) * 9 + ky * 3 + kx];
                }
            }
        }
#pragma unroll
        for (int co = 0; co < KOFF; ++co) {
            float v = acc[co];
            v += __shfl_xor(v, 1);
            v += __shfl_xor(v, 2);
            v += __shfl_xor(v, 4);
            if (c8 == 0) offlds[co * PXB + px] = v + b_off[co];
        }
    }
    __syncthreads();

    for (int e = t; e < 9 * PXB; e += 256) {
        int tap = e >> 5;
        int px  = e & 31;
        float offy = offlds[(2 * tap) * PXB + px];
        float offx = offlds[(2 * tap + 1) * PXB + px];
        float py  = offy + (float)(tap / 3) + (float)(ho - 1);
        float pxf = offx + (float)(tap % 3) + (float)(half * PXB + px - 1);
        float fy = floorf(py), fx = floorf(pxf);
        int y0 = (int)fy, x0 = (int)fx;
        float wy1 = py - fy, wx1 = pxf - fx;
        float wy0 = 1.f - wy1, wx0 = 1.f - wx1;
        bool y0ok = ((unsigned)y0 < (unsigned)HDIM);
        bool x0ok = ((unsigned)x0 < (unsigned)WDIM);
        bool y1ok = ((unsigned)(y0 + 1) < (unsigned)HDIM);
        bool x1ok = ((unsigned)(x0 + 1) < (unsigned)WDIM);
        float w00 = (y0ok && x0ok) ? wy0 * wx0 : 0.f;
        float w01 = (y0ok && x1ok) ? wy0 * wx1 : 0.f;
        float w10 = (y1ok && x0ok) ? wy1 * wx0 : 0.f;
        float w11 = (y1ok && x1ok) ? wy1 * wx1 : 0.f;
        int yc0 = min(max(y0, 0), HDIM - 1);
        int xc0 = min(max(x0, 0), WDIM - 1);
        int yc1 = min(max(y0 + 1, 0), HDIM - 1);
        int xc1 = min(max(x0 + 1, 0), WDIM - 1);
        union { __half2 h; unsigned u; } c0, c1;
        c0.h = __floats2half2_rn(w00, w01);
        c1.h = __floats2half2_rn(w10, w11);
        uint4 rec;
        rec.x = (unsigned)(yc0 * WDIM + xc0) | ((unsigned)(xc1 - xc0) << 12)
              | ((unsigned)(yc1 - yc0) << 13);
        rec.y = c0.u;
        rec.z = c1.u;
        rec.w = 0u;
        grec[tap * GSTR + px] = rec;
    }
    __syncthreads();

    const int gi = t >> 5;
    const int px = t & 31;
    const int wco = t >> 2;
    const int wk  = (t & 3) * 8;
    floatx4 acc0 = {0.f, 0.f, 0.f, 0.f};
    floatx4 acc1 = {0.f, 0.f, 0.f, 0.f};

    for (int kg0 = 0; kg0 < 576; kg0 += 32) {
        {
            const float4* ws4 = (const float4*)&w_dcn[wco * 576 + kg0 + wk];
            float4 f0 = ws4[0], f1 = ws4[1];
            half8 wv;
            wv[0] = (_Float16)f0.x; wv[1] = (_Float16)f0.y;
            wv[2] = (_Float16)f0.z; wv[3] = (_Float16)f0.w;
            wv[4] = (_Float16)f1.x; wv[5] = (_Float16)f1.y;
            wv[6] = (_Float16)f1.z; wv[7] = (_Float16)f1.w;
            *(half8*)&wlds[wco * CPAD + wk] = wv;
        }
        half4 vb;
#pragma unroll
        for (int j = 0; j < 4; ++j) {
            int k   = kg0 + gi * 4 + j;
            int cin = k / 9;
            int tap = k - cin * 9;
            const float* xc = xb + (size_t)cin * (HDIM * WDIM);
            uint4 rr = grec[tap * GSTR + px];
            unsigned base = rr.x & 0xfffu;
            unsigned dx   = (rr.x >> 12) & 1u;
            unsigned dy64 = (rr.x >> 7) & 64u;
            union { unsigned u; __half2 h; } c0, c1;
            c0.u = rr.y; c1.u = rr.z;
            float v00 = xc[base];
            float v01 = xc[base + dx];
            float v10 = xc[base + dy64];
            float v11 = xc[base + dy64 + dx];
            float v = v00 * (float)c0.h.x + v01 * (float)c0.h.y
                    + v10 * (float)c1.h.x + v11 * (float)c1.h.y;
            vb[j] = (_Float16)v;
        }
        *(half4*)&colsT[px * CPAD + gi * 4] = vb;
        __syncthreads();

        half8 afrag = *(const half8*)&wlds[(wid * 16 + (lane & 15)) * CPAD + (lane >> 4) * 8];
        half8 b0 = *(const half8*)&colsT[(lane & 15) * CPAD + (lane >> 4) * 8];
        half8 b1 = *(const half8*)&colsT[(16 + (lane & 15)) * CPAD + (lane >> 4) * 8];
        acc0 = __builtin_amdgcn_mfma_f32_16x16x32_f16(afrag, b0, acc0, 0, 0, 0);
        acc1 = __builtin_amdgcn_mfma_f32_16x16x32_f16(afrag, b1, acc1, 0, 0, 0);
        __syncthreads();
    }

    const int col = lane & 15;
    const int r0  = (lane >> 4) * 4;
#pragma unroll
    for (int r = 0; r < 4; ++r) {
        int co = wid * 16 + r0 + r;
        float bias = b_dcn[co];
        size_t o = (((size_t)b * 64 + co) * HDIM + ho) * WDIM + half * PXB;
        out[o + col]      = acc0[r] + bias;
        out[o + 16 + col] = acc1[r] + bias;
    }
}

// ---------------------------------------------------------------------------
extern "C" void kernel_launch(void* const* d_in, const int* in_sizes, int n_in,
                              void* d_out, int out_size, void* d_ws, size_t ws_size,
                              hipStream_t stream) {
    const float* x     = (const float*)d_in[0];
    const float* w_off = (const float*)d_in[1];
    const float* b_off = (const float*)d_in[2];
    const float* w_dcn = (const float*)d_in[3];
    const float* b_dcn = (const float*)d_in[4];
    float* out = (float*)d_out;

    char* ws = (char*)d_ws;
    _Float16* w2t    = (_Float16*)ws;
    _Float16* woff2t = (_Float16*)(ws + WOFF2T_OFF);
    uint4*    grecs  = (uint4*)(ws + GREC_OFF);

    if (ws_size >= (size_t)WS_NEED) {
        cvt_w<<<216, 256, 0, stream>>>(w_dcn, w_off, w2t, woff2t);
        dcn_offsets<<<1024, 256, 0, stream>>>(x, woff2t, b_off, grecs);
        dcn_gemm<<<2048, 256, 0, stream>>>(x, w2t, grecs, b_dcn, out);
    } else {
        dcn_fused<<<2048, 256, 0, stream>>>(x, w_off, b_off, w_dcn, b_dcn, out);
    }
}

// Round 9
// 196.248 us; speedup vs baseline: 1.2151x; 1.2151x over previous
//
#include <hip/hip_runtime.h>
#include <hip/hip_fp16.h>

// DeformConv2d: B=16, Cin=64, Cout=64, H=W=64, K=3, stride=1, pad=1, dil=1
// Round 9: SINGLE fused kernel (launch overhead ~25us/kernel was ~75us of
// the 238). K reordered as k' = tap*64 + cin so that:
//   - tap is COMPILE-TIME in the unrolled k-loop -> geometry regs statically
//     indexed (R8's dynamic-index select-chain bug fixed)
//   - cin is wave-uniform -> gather loads are saddr + 32-bit lane offset,
//     neighbor offsets hoisted per tap (~6 VALU/sample)
// Phase A = MFMA offset conv (reuses colsT LDS, pre-warms x rows).
// Double-buffered colsT, 1 barrier/iter. No geometry ws round-trip.

#define HDIM 64
#define WDIM 64
#define KOFF 18
#define CPAD 40          // padded k-stride (halfs): 80B rows
#define NIT  18          // k-groups of 32 (k' = tap*64 + cin)

#define W2T_HALFS    (18 * 64 * 32)     // [i][64co][32kl]
#define WOFF2T_HALFS (18 * 32 * 32)     // [i][32co][32kl]
#define W2T_BYTES    (W2T_HALFS * 2)    // 73728
#define WOFF2T_OFF   W2T_BYTES
#define WS_NEED      (W2T_BYTES + WOFF2T_HALFS * 2)   // 110592

typedef _Float16 half8 __attribute__((ext_vector_type(8)));
typedef float floatx4 __attribute__((ext_vector_type(4)));

// ---------------------------------------------------------------------------
// weight prep: tap-major K order. i = k-group (0..17): tap = i>>1,
// cin = (i&1)*32 + kl.
__global__ void cvt_w(const float* __restrict__ w_dcn,
                      const float* __restrict__ w_off,
                      _Float16* __restrict__ w2t,
                      _Float16* __restrict__ woff2t) {
    int e = blockIdx.x * 256 + threadIdx.x;       // 216*256 = 55296 exactly
    if (e < W2T_HALFS) {
        int kl = e & 31, co = (e >> 5) & 63, i = e >> 11;
        int tap = i >> 1, cin = (i & 1) * 32 + kl;
        w2t[e] = (_Float16)w_dcn[co * 576 + cin * 9 + tap];
    } else {
        int e2 = e - W2T_HALFS;
        int kl = e2 & 31, co = (e2 >> 5) & 31, i = e2 >> 10;
        int tap = i >> 1, cin = (i & 1) * 32 + kl;
        woff2t[e2] = (co < KOFF) ? (_Float16)w_off[co * 576 + cin * 9 + tap]
                                 : (_Float16)0.f;
    }
}

// ---------------------------------------------------------------------------
__launch_bounds__(256)
__global__ void dcn_fused(const float* __restrict__ x,
                          const _Float16* __restrict__ w2t,
                          const _Float16* __restrict__ woff2t,
                          const float* __restrict__ w_dcn,
                          const float* __restrict__ w_off,
                          const float* __restrict__ b_off,
                          const float* __restrict__ b_dcn,
                          float* __restrict__ out,
                          int use_wt) {
    // XCD swizzle: 2 consecutive batches per XCD (2MB x slice fits 4MB L2)
    const int bid  = blockIdx.x;                 // 0..1023
    const int slot = bid >> 3;                   // 0..127
    const int b    = ((bid & 7) << 1) | (slot >> 6);
    const int ho   = slot & 63;
    const int t    = threadIdx.x;
    const int lane = t & 63;
    const int wid  = __builtin_amdgcn_readfirstlane(t >> 6);
    const int r    = lane & 15;
    const int q    = lane >> 4;

    __shared__ __align__(16) _Float16 colsT[2][64 * CPAD];  // 10240 B
    __shared__ __align__(16) float    offlds[KOFF * 64];    // 4608 B

    const float* xb = x + (size_t)b * 64 * 4096;

    // ================= Phase A: offset conv via MFMA =================
    {
        _Float16* colsA = colsT[0];
        floatx4 am0 = {0.f, 0.f, 0.f, 0.f};
        floatx4 am1 = {0.f, 0.f, 0.f, 0.f};
#pragma unroll
        for (int i = 0; i < NIT; ++i) {
            const int tap = i >> 1;
            const int dy  = tap / 3, dxk = tap - dy * 3;
            const int y   = ho + dy - 1;
            const bool yok = ((unsigned)y < 64u);
            const float* xrow = xb + ((size_t)((i & 1) * 32 + wid * 8)) * 4096
                                   + y * 64;
            const int xc = lane + dxk - 1;
            const bool ok = yok && ((unsigned)xc < 64u);
            half8 hv;
#pragma unroll
            for (int j = 0; j < 8; ++j) {
                float v = ok ? xrow[(size_t)j * 4096 + xc] : 0.f;
                hv[j] = (_Float16)v;
            }
            *(half8*)&colsA[lane * CPAD + wid * 8] = hv;
            __syncthreads();

            half8 bfr = *(const half8*)&colsA[(wid * 16 + r) * CPAD + q * 8];
            half8 a0, a1;
            if (use_wt) {
                a0 = *(const half8*)&woff2t[i * 1024 + r * 32 + q * 8];
                a1 = *(const half8*)&woff2t[i * 1024 + (16 + r) * 32 + q * 8];
            } else {
                const int cin0 = (i & 1) * 32 + q * 8;
#pragma unroll
                for (int j = 0; j < 8; ++j) {
                    a0[j] = (r < KOFF)
                          ? (_Float16)w_off[r * 576 + (cin0 + j) * 9 + tap]
                          : (_Float16)0.f;
                    a1[j] = (_Float16)0.f;    // co 16..31 all >= KOFF except 16,17
                }
                if (16 + r < KOFF) {
#pragma unroll
                    for (int j = 0; j < 8; ++j)
                        a1[j] = (_Float16)w_off[(16 + r) * 576 + (cin0 + j) * 9 + tap];
                }
            }
            am0 = __builtin_amdgcn_mfma_f32_16x16x32_f16(a0, bfr, am0, 0, 0, 0);
            am1 = __builtin_amdgcn_mfma_f32_16x16x32_f16(a1, bfr, am1, 0, 0, 0);
            __syncthreads();
        }
        // D[m=co][n=px]: col r -> px tile of wave wid, row q*4+reg -> co
        const int pxg = wid * 16 + r;
#pragma unroll
        for (int reg = 0; reg < 4; ++reg) {
            int co = q * 4 + reg;
            offlds[co * 64 + pxg] = am0[reg] + b_off[co];
            int co2 = 16 + q * 4 + reg;
            if (co2 < KOFF)
                offlds[co2 * 64 + pxg] = am1[reg] + b_off[co2];
        }
    }
    __syncthreads();

    // ================= Geometry -> registers (static indices) ========
    unsigned rmeta[9], rw0[9], rw1[9];
    {
        const int px = lane;
#pragma unroll
        for (int tap = 0; tap < 9; ++tap) {
            float offy = offlds[(2 * tap) * 64 + px];
            float offx = offlds[(2 * tap + 1) * 64 + px];
            float py  = offy + (float)(tap / 3) + (float)(ho - 1);
            float pxf = offx + (float)(tap % 3) + (float)(px - 1);
            float fy = floorf(py), fx = floorf(pxf);
            int y0 = (int)fy, x0 = (int)fx;
            float wy1 = py - fy, wx1 = pxf - fx;
            float wy0 = 1.f - wy1, wx0 = 1.f - wx1;
            bool y0ok = ((unsigned)y0 < 64u);
            bool x0ok = ((unsigned)x0 < 64u);
            bool y1ok = ((unsigned)(y0 + 1) < 64u);
            bool x1ok = ((unsigned)(x0 + 1) < 64u);
            float w00 = (y0ok && x0ok) ? wy0 * wx0 : 0.f;
            float w01 = (y0ok && x1ok) ? wy0 * wx1 : 0.f;
            float w10 = (y1ok && x0ok) ? wy1 * wx0 : 0.f;
            float w11 = (y1ok && x1ok) ? wy1 * wx1 : 0.f;
            int yc0 = min(max(y0, 0), 63);
            int xc0 = min(max(x0, 0), 63);
            int yc1 = min(max(y0 + 1, 0), 63);
            int xc1 = min(max(x0 + 1, 0), 63);
            union { __half2 h; unsigned u; } c0, c1;
            c0.h = __floats2half2_rn(w00, w01);
            c1.h = __floats2half2_rn(w10, w11);
            rmeta[tap] = (unsigned)(yc0 * 64 + xc0)
                       | ((unsigned)(xc1 - xc0) << 12)
                       | ((unsigned)(yc1 - yc0) << 13);
            rw0[tap] = c0.u;
            rw1[tap] = c1.u;
        }
    }

    // ================= Phase B: gather + MFMA (dbuf, 1 barrier/iter) =
    floatx4 acc[4];
#pragma unroll
    for (int nt = 0; nt < 4; ++nt) acc[nt] = (floatx4){0.f, 0.f, 0.f, 0.f};

    auto gather = [&](int i) {
        const int tap = i >> 1;                 // compile-time under unroll
        const unsigned m = rmeta[tap];
        const unsigned a00 = (m & 0xfffu) << 2;         // byte offsets
        const unsigned a01 = a00 + ((m >> 10) & 4u);
        const unsigned a10 = a00 + ((m >> 5) & 256u);
        const unsigned a11 = a10 + ((m >> 10) & 4u);
        union { unsigned u; __half2 h; } c0, c1;
        c0.u = rw0[tap]; c1.u = rw1[tap];
        const float wA = __half2float(c0.h.x), wB = __half2float(c0.h.y);
        const float wC = __half2float(c1.h.x), wD = __half2float(c1.h.y);
        const char* xpl = (const char*)(xb + ((size_t)((i & 1) * 32 + wid * 8)) * 4096);
        half8 hv;
#pragma unroll
        for (int j = 0; j < 8; ++j) {
            const char* xp = xpl + (size_t)j * 16384;
            float v00 = *(const float*)(xp + a00);
            float v01 = *(const float*)(xp + a01);
            float v10 = *(const float*)(xp + a10);
            float v11 = *(const float*)(xp + a11);
            hv[j] = (_Float16)(v00 * wA + v01 * wB + v10 * wC + v11 * wD);
        }
        *(half8*)&colsT[i & 1][lane * CPAD + wid * 8] = hv;
    };

    auto load_af = [&](int i) -> half8 {
        if (use_wt) {
            return *(const half8*)&w2t[(size_t)i * 2048 + (wid * 16 + r) * 32 + q * 8];
        } else {
            const int tap = i >> 1;
            const int cin0 = (i & 1) * 32 + q * 8;
            half8 v;
#pragma unroll
            for (int j = 0; j < 8; ++j)
                v[j] = (_Float16)w_dcn[(wid * 16 + r) * 576 + (cin0 + j) * 9 + tap];
            return v;
        }
    };

    half8 af = load_af(0);
    gather(0);
    __syncthreads();

#pragma unroll
    for (int i = 0; i < NIT - 1; ++i) {
        half8 afn = load_af(i + 1);
        gather(i + 1);
#pragma unroll
        for (int nt = 0; nt < 4; ++nt) {
            half8 bfr = *(const half8*)&colsT[i & 1][(nt * 16 + r) * CPAD + q * 8];
            acc[nt] = __builtin_amdgcn_mfma_f32_16x16x32_f16(af, bfr, acc[nt], 0, 0, 0);
        }
        af = afn;
        __syncthreads();
    }
#pragma unroll
    for (int nt = 0; nt < 4; ++nt) {
        half8 bfr = *(const half8*)&colsT[(NIT - 1) & 1][(nt * 16 + r) * CPAD + q * 8];
        acc[nt] = __builtin_amdgcn_mfma_f32_16x16x32_f16(af, bfr, acc[nt], 0, 0, 0);
    }

    // ================= epilogue =====================================
#pragma unroll
    for (int reg = 0; reg < 4; ++reg) {
        int co = wid * 16 + q * 4 + reg;
        float bias = b_dcn[co];
        size_t o = (((size_t)b * 64 + co) * 64 + ho) * 64;
#pragma unroll
        for (int nt = 0; nt < 4; ++nt)
            out[o + nt * 16 + r] = acc[nt][reg] + bias;
    }
}

// ---------------------------------------------------------------------------
extern "C" void kernel_launch(void* const* d_in, const int* in_sizes, int n_in,
                              void* d_out, int out_size, void* d_ws, size_t ws_size,
                              hipStream_t stream) {
    const float* x     = (const float*)d_in[0];
    const float* w_off = (const float*)d_in[1];
    const float* b_off = (const float*)d_in[2];
    const float* w_dcn = (const float*)d_in[3];
    const float* b_dcn = (const float*)d_in[4];
    float* out = (float*)d_out;

    char* ws = (char*)d_ws;
    _Float16* w2t    = (_Float16*)ws;
    _Float16* woff2t = (_Float16*)(ws + WOFF2T_OFF);

    int use_wt = (ws_size >= (size_t)WS_NEED) ? 1 : 0;
    if (use_wt) {
        cvt_w<<<216, 256, 0, stream>>>(w_dcn, w_off, w2t, woff2t);
    }
    dcn_fused<<<1024, 256, 0, stream>>>(x, w2t, woff2t, w_dcn, w_off,
                                        b_off, b_dcn, out, use_wt);
}

// Round 11
// 195.326 us; speedup vs baseline: 1.2208x; 1.0047x over previous
//
#include <hip/hip_runtime.h>
#include <hip/hip_fp16.h>

// DeformConv2d: B=16, Cin=64, Cout=64, H=W=64, K=3, stride=1, pad=1, dil=1
// Round 11: isolation round. R10 failed correctness (absmax 0.242) after
// changing (a) load batching, (b) pair-record encoding, (c) phase-A N=32
// restructure together. This round keeps (a)+(c) and reverts ONLY (b) to
// R9's proven record encoding: rmeta = clamped base | dx<<12 | dy<<13,
// weights = validity-folded f16 products (w00,w01),(w10,w11); gather does
// 4 scalar loads per sample, ALL 16 loads batched before any math.

#define KOFF 18
#define CPAD 40          // padded k-stride (halfs): 80B rows
#define NIT  18          // k-groups of 32; k' = tap*64 + cin (tap = i>>1)

#define W2T_HALFS    (18 * 64 * 32)     // [i][64co][32kl]
#define WOFF2T_HALFS (18 * 32 * 32)     // [i][32co][32kl]
#define W2T_BYTES    (W2T_HALFS * 2)
#define WOFF2T_OFF   W2T_BYTES
#define WS_NEED      (W2T_BYTES + WOFF2T_HALFS * 2)   // 110592

typedef _Float16 half8 __attribute__((ext_vector_type(8)));
typedef _Float16 half4 __attribute__((ext_vector_type(4)));
typedef float floatx4 __attribute__((ext_vector_type(4)));

// ---------------------------------------------------------------------------
__global__ void cvt_w(const float* __restrict__ w_dcn,
                      const float* __restrict__ w_off,
                      _Float16* __restrict__ w2t,
                      _Float16* __restrict__ woff2t) {
    int e = blockIdx.x * 256 + threadIdx.x;       // 216*256 = 55296 exactly
    if (e < W2T_HALFS) {
        int kl = e & 31, co = (e >> 5) & 63, i = e >> 11;
        int tap = i >> 1, cin = (i & 1) * 32 + kl;
        w2t[e] = (_Float16)w_dcn[co * 576 + cin * 9 + tap];
    } else {
        int e2 = e - W2T_HALFS;
        int kl = e2 & 31, co = (e2 >> 5) & 31, i = e2 >> 10;
        int tap = i >> 1, cin = (i & 1) * 32 + kl;
        woff2t[e2] = (co < KOFF) ? (_Float16)w_off[co * 576 + cin * 9 + tap]
                                 : (_Float16)0.f;
    }
}

// ---------------------------------------------------------------------------
__launch_bounds__(256, 4)
__global__ void dcn_fused(const float* __restrict__ x,
                          const _Float16* __restrict__ w2t,
                          const _Float16* __restrict__ woff2t,
                          const float* __restrict__ w_dcn,
                          const float* __restrict__ w_off,
                          const float* __restrict__ b_off,
                          const float* __restrict__ b_dcn,
                          float* __restrict__ out,
                          int use_wt) {
    // XCD swizzle: 2 consecutive batches per XCD (2MB x slice fits 4MB L2)
    const int bid  = blockIdx.x;                 // 0..2047
    const int s    = bid >> 3;                   // 0..255
    const int b    = ((bid & 7) << 1) | (s >> 7);
    const int ho   = (s >> 1) & 63;
    const int hlf  = s & 1;
    const int t    = threadIdx.x;
    const int lane = t & 63;
    const int wid  = __builtin_amdgcn_readfirstlane(t >> 6);
    const int r    = lane & 15;
    const int q    = lane >> 4;
    const int px   = t & 31;                     // staging/gather pixel
    const int kq   = t >> 5;                     // k-quad group 0..7

    __shared__ __align__(16) _Float16 colsT[2][32 * CPAD];  // 5120 B
    __shared__ __align__(16) float    offlds[KOFF * 32];    // 2304 B

    const float* xb = x + (size_t)b * 64 * 4096;
    const int pxg = hlf * 32;                    // global px base

    // ================= Phase A: offset conv via MFMA (M=32,N=32,K=576) ====
    {
        floatx4 am = {0.f, 0.f, 0.f, 0.f};
        const int m = wid & 1;                   // co tile
        const int n = wid >> 1;                  // px tile

        auto stageA = [&](int i) {
            const int tap = i >> 1;
            const int dy = tap / 3, dxk = tap - dy * 3;
            const int y  = ho + dy - 1;
            const int xc = pxg + px + dxk - 1;
            const bool ok = ((unsigned)y < 64u) && ((unsigned)xc < 64u);
            const float* xp = xb + ((size_t)((i & 1) * 32 + kq * 4)) * 4096
                                 + y * 64 + xc;
            float va[4];
#pragma unroll
            for (int j = 0; j < 4; ++j) va[j] = ok ? xp[(size_t)j * 4096] : 0.f;
            half4 hv;
#pragma unroll
            for (int j = 0; j < 4; ++j) hv[j] = (_Float16)va[j];
            *(half4*)&colsT[i & 1][px * CPAD + kq * 4] = hv;
        };

        auto loadA = [&](int i) -> half8 {
            if (use_wt)
                return *(const half8*)&woff2t[i * 1024 + (m * 16 + r) * 32 + q * 8];
            const int tap = i >> 1;
            const int cin0 = (i & 1) * 32 + q * 8;
            const int co = m * 16 + r;
            half8 v;
#pragma unroll
            for (int j = 0; j < 8; ++j)
                v[j] = (co < KOFF) ? (_Float16)w_off[co * 576 + (cin0 + j) * 9 + tap]
                                   : (_Float16)0.f;
            return v;
        };

        stageA(0);
        half8 a = loadA(0);
        __syncthreads();
#pragma unroll
        for (int i = 0; i < NIT; ++i) {
            if (i < NIT - 1) stageA(i + 1);
            half8 an = (i < NIT - 1) ? loadA(i + 1) : a;
            half8 bfr = *(const half8*)&colsT[i & 1][(n * 16 + r) * CPAD + q * 8];
            am = __builtin_amdgcn_mfma_f32_16x16x32_f16(a, bfr, am, 0, 0, 0);
            a = an;
            __syncthreads();
        }
        // D[m=co][n=px]: col=r -> px, row=q*4+reg -> co
#pragma unroll
        for (int reg = 0; reg < 4; ++reg) {
            int co = m * 16 + q * 4 + reg;
            if (co < KOFF)
                offlds[co * 32 + (n * 16 + r)] = am[reg] + b_off[co];
        }
    }
    __syncthreads();

    // ====== Geometry -> registers (R9-proven encoding, static indices) ====
    unsigned rmeta[9], rw0[9], rw1[9];
#pragma unroll
    for (int tap = 0; tap < 9; ++tap) {
        float offy = offlds[(2 * tap) * 32 + px];
        float offx = offlds[(2 * tap + 1) * 32 + px];
        float py  = offy + (float)(tap / 3) + (float)(ho - 1);
        float pxf = offx + (float)(tap % 3) + (float)(pxg + px - 1);
        float fy = floorf(py), fx = floorf(pxf);
        int y0 = (int)fy, x0 = (int)fx;
        float wy1 = py - fy, wx1 = pxf - fx;
        float wy0 = 1.f - wy1, wx0 = 1.f - wx1;
        bool y0ok = ((unsigned)y0 < 64u);
        bool x0ok = ((unsigned)x0 < 64u);
        bool y1ok = ((unsigned)(y0 + 1) < 64u);
        bool x1ok = ((unsigned)(x0 + 1) < 64u);
        float w00 = (y0ok && x0ok) ? wy0 * wx0 : 0.f;
        float w01 = (y0ok && x1ok) ? wy0 * wx1 : 0.f;
        float w10 = (y1ok && x0ok) ? wy1 * wx0 : 0.f;
        float w11 = (y1ok && x1ok) ? wy1 * wx1 : 0.f;
        int yc0 = min(max(y0, 0), 63);
        int xc0 = min(max(x0, 0), 63);
        int yc1 = min(max(y0 + 1, 0), 63);
        int xc1 = min(max(x0 + 1, 0), 63);
        union { __half2 h; unsigned u; } c0, c1;
        c0.h = __floats2half2_rn(w00, w01);
        c1.h = __floats2half2_rn(w10, w11);
        rmeta[tap] = (unsigned)(yc0 * 64 + xc0)
                   | ((unsigned)(xc1 - xc0) << 12)
                   | ((unsigned)(yc1 - yc0) << 13);
        rw0[tap] = c0.u;
        rw1[tap] = c1.u;
    }

    // ================= Phase B: gather + MFMA (dbuf, 1 barrier/iter) =====
    floatx4 acc0 = {0.f, 0.f, 0.f, 0.f};
    floatx4 acc1 = {0.f, 0.f, 0.f, 0.f};

    auto gather = [&](int i) {
        const int tap = i >> 1;                 // compile-time under unroll
        const unsigned m = rmeta[tap];
        const unsigned a00 = (m & 0xfffu) << 2;
        const unsigned a01 = a00 + ((m >> 10) & 4u);
        const unsigned a10 = a00 + ((m >> 5) & 256u);
        const unsigned a11 = a10 + ((m >> 10) & 4u);
        const char* base = (const char*)xb
                         + ((size_t)((i & 1) * 32 + kq * 4)) * 16384;
        // batch ALL loads before any math -> single waitcnt
        float v00[4], v01[4], v10[4], v11[4];
#pragma unroll
        for (int j = 0; j < 4; ++j) {
            const char* xp = base + (size_t)j * 16384;
            v00[j] = *(const float*)(xp + a00);
            v01[j] = *(const float*)(xp + a01);
            v10[j] = *(const float*)(xp + a10);
            v11[j] = *(const float*)(xp + a11);
        }
        union { unsigned u; __half2 h; } c0, c1;
        c0.u = rw0[tap]; c1.u = rw1[tap];
        const float wA = __half2float(c0.h.x), wB = __half2float(c0.h.y);
        const float wC = __half2float(c1.h.x), wD = __half2float(c1.h.y);
        half4 hv;
#pragma unroll
        for (int j = 0; j < 4; ++j)
            hv[j] = (_Float16)(v00[j] * wA + v01[j] * wB
                             + v10[j] * wC + v11[j] * wD);
        *(half4*)&colsT[i & 1][px * CPAD + kq * 4] = hv;
    };

    auto load_af = [&](int i) -> half8 {
        if (use_wt)
            return *(const half8*)&w2t[(size_t)i * 2048 + (wid * 16 + r) * 32 + q * 8];
        const int tap = i >> 1;
        const int cin0 = (i & 1) * 32 + q * 8;
        half8 v;
#pragma unroll
        for (int j = 0; j < 8; ++j)
            v[j] = (_Float16)w_dcn[(wid * 16 + r) * 576 + (cin0 + j) * 9 + tap];
        return v;
    };

    half8 af = load_af(0);
    gather(0);
    __syncthreads();

#pragma unroll
    for (int i = 0; i < NIT; ++i) {
        half8 afn = af;
        if (i < NIT - 1) { afn = load_af(i + 1); gather(i + 1); }
        half8 b0 = *(const half8*)&colsT[i & 1][r * CPAD + q * 8];
        half8 b1 = *(const half8*)&colsT[i & 1][(16 + r) * CPAD + q * 8];
        acc0 = __builtin_amdgcn_mfma_f32_16x16x32_f16(af, b0, acc0, 0, 0, 0);
        acc1 = __builtin_amdgcn_mfma_f32_16x16x32_f16(af, b1, acc1, 0, 0, 0);
        af = afn;
        if (i < NIT - 1) __syncthreads();
    }

    // ================= epilogue =====================================
#pragma unroll
    for (int reg = 0; reg < 4; ++reg) {
        int co = wid * 16 + q * 4 + reg;
        float bias = b_dcn[co];
        size_t o = (((size_t)b * 64 + co) * 64 + ho) * 64 + pxg;
        out[o + r]      = acc0[reg] + bias;
        out[o + 16 + r] = acc1[reg] + bias;
    }
}

// ---------------------------------------------------------------------------
extern "C" void kernel_launch(void* const* d_in, const int* in_sizes, int n_in,
                              void* d_out, int out_size, void* d_ws, size_t ws_size,
                              hipStream_t stream) {
    const float* x     = (const float*)d_in[0];
    const float* w_off = (const float*)d_in[1];
    const float* b_off = (const float*)d_in[2];
    const float* w_dcn = (const float*)d_in[3];
    const float* b_dcn = (const float*)d_in[4];
    float* out = (float*)d_out;

    char* ws = (char*)d_ws;
    _Float16* w2t    = (_Float16*)ws;
    _Float16* woff2t = (_Float16*)(ws + WOFF2T_OFF);

    int use_wt = (ws_size >= (size_t)WS_NEED) ? 1 : 0;
    if (use_wt) {
        cvt_w<<<216, 256, 0, stream>>>(w_dcn, w_off, w2t, woff2t);
    }
    dcn_fused<<<2048, 256, 0, stream>>>(x, w2t, woff2t, w_dcn, w_off,
                                        b_off, b_dcn, out, use_wt);
}

// Round 12
// 123.516 us; speedup vs baseline: 1.9306x; 1.5814x over previous
//
#include <hip/hip_runtime.h>
#include <hip/hip_fp16.h>

// DeformConv2d: B=16, Cin=64, Cout=64, H=W=64, K=3, stride=1, pad=1, dil=1
// Round 12: the kernel is VMEM-INSTRUCTION-COUNT bound (R11: 17 VMEM/thr/iter
// x 16cyc TA = measured 131us exactly). Fix: NHWC f16 copy of x in ws ->
// one half8 load = 8 cin values at a sampling point. Phase B: 4 gather loads
// per tap (vs 32), bilinear via packed __hfma2. Records via LDS (R9-proven
// encoding). 9-tap loop, 1 barrier/iter, double-buffered colsT.

#define KOFF 18
#define CPAD 72            // halfs per px row in colsT (64 cin + 8 pad)
#define GSTR 33            // LDS geometry record stride (uint4)

#define W2T_HALFS    (18 * 64 * 32)     // [i][64co][32kl], k' = tap*64+cin
#define WOFF2T_HALFS (18 * 32 * 32)     // [i][32co][32kl]
#define W2T_BYTES    (W2T_HALFS * 2)    // 73728
#define WOFF2T_OFF   W2T_BYTES
#define X_OFF        (W2T_BYTES + WOFF2T_HALFS * 2)   // 110592 (16B aligned)
#define XH_BYTES     (16 * 64 * 64 * 64 * 2)          // 8388608
#define WS_NEED      (X_OFF + XH_BYTES)               // 8499200

typedef _Float16 half8 __attribute__((ext_vector_type(8)));
typedef float floatx4 __attribute__((ext_vector_type(4)));

union H8 { half8 v; __half2 h2[4]; uint4 u; };

// ---------------------------------------------------------------------------
// prep: x NCHW f32 -> NHWC f16 (xh), weights -> tap-major f16.
// grid 16384 x 256 == 4,194,304 threads == |x| exactly.
__global__ void prep(const float* __restrict__ x,
                     const float* __restrict__ w_dcn,
                     const float* __restrict__ w_off,
                     _Float16* __restrict__ w2t,
                     _Float16* __restrict__ woff2t,
                     _Float16* __restrict__ xh) {
    int e = blockIdx.x * 256 + threadIdx.x;
    {   // x transpose: e = b(4) cin(6) y(6) x(6), coalesced read
        int xx = e & 63, y = (e >> 6) & 63, cin = (e >> 12) & 63, b = e >> 18;
        xh[((((size_t)b * 64 + y) * 64 + xx) << 6) + cin] = (_Float16)x[e];
    }
    if (e < W2T_HALFS) {
        int kl = e & 31, co = (e >> 5) & 63, i = e >> 11;
        int tap = i >> 1, cin = (i & 1) * 32 + kl;
        w2t[e] = (_Float16)w_dcn[co * 576 + cin * 9 + tap];
    } else if (e < W2T_HALFS + WOFF2T_HALFS) {
        int e2 = e - W2T_HALFS;
        int kl = e2 & 31, co = (e2 >> 5) & 31, i = e2 >> 10;
        int tap = i >> 1, cin = (i & 1) * 32 + kl;
        woff2t[e2] = (co < KOFF) ? (_Float16)w_off[co * 576 + cin * 9 + tap]
                                 : (_Float16)0.f;
    }
}

// ---------------------------------------------------------------------------
__launch_bounds__(256, 4)
__global__ void dcn_main(const _Float16* __restrict__ xh,
                         const _Float16* __restrict__ w2t,
                         const _Float16* __restrict__ woff2t,
                         const float* __restrict__ b_off,
                         const float* __restrict__ b_dcn,
                         float* __restrict__ out) {
    const int bid = blockIdx.x;                 // 0..2047
    const int s   = bid >> 3;
    const int b   = ((bid & 7) << 1) | (s >> 7);
    const int ho  = (s >> 1) & 63;
    const int hlf = s & 1;
    const int t    = threadIdx.x;
    const int lane = t & 63;
    const int wid  = __builtin_amdgcn_readfirstlane(t >> 6);
    const int r    = lane & 15;
    const int q    = lane >> 4;
    const int gpx  = t >> 3;                    // 0..31 gather/stage pixel
    const int oct  = t & 7;                     // 8-cin octet
    const int pxg  = hlf * 32;

    __shared__ __align__(16) _Float16 colsT[2][32 * CPAD];  // 9216 B
    __shared__ __align__(16) float    offlds[KOFF * 32];    // 2304 B
    __shared__ __align__(16) uint4    grecL[9 * GSTR];      // 4752 B

    const _Float16* xb = xh + ((size_t)b << 18);
    const char* xpb = (const char*)xb;

    // ================= Phase A: offset conv via MFMA =====================
    {
        floatx4 am = {0.f, 0.f, 0.f, 0.f};
        const int m = wid & 1, n = wid >> 1;

        auto stageA = [&](int tap) {
            const int dy = tap / 3, dxk = tap - dy * 3;
            const int y  = ho + dy - 1;
            const int xc = pxg + gpx + dxk - 1;
            half8 v = {};
            if (((unsigned)y < 64u) && ((unsigned)xc < 64u))
                v = *(const half8*)&xb[(((size_t)y * 64 + xc) << 6) + oct * 8];
            *(half8*)&colsT[tap & 1][gpx * CPAD + oct * 8] = v;
        };

        stageA(0);
        __syncthreads();
#pragma unroll
        for (int tap = 0; tap < 9; ++tap) {
            if (tap < 8) stageA(tap + 1);
#pragma unroll
            for (int g = 0; g < 2; ++g) {
                half8 a = *(const half8*)&woff2t[(tap * 2 + g) * 1024
                                                 + (m * 16 + r) * 32 + q * 8];
                half8 bf = *(const half8*)&colsT[tap & 1][(n * 16 + r) * CPAD
                                                          + g * 32 + q * 8];
                am = __builtin_amdgcn_mfma_f32_16x16x32_f16(a, bf, am, 0, 0, 0);
            }
            __syncthreads();
        }
#pragma unroll
        for (int reg = 0; reg < 4; ++reg) {
            int co = m * 16 + q * 4 + reg;
            if (co < KOFF)
                offlds[co * 32 + n * 16 + r] = am[reg] + b_off[co];
        }
    }
    __syncthreads();

    // ================= Geometry records (R9-proven encoding) =============
    for (int e = t; e < 9 * 32; e += 256) {
        int tap = e >> 5, px = e & 31;
        float offy = offlds[(2 * tap) * 32 + px];
        float offx = offlds[(2 * tap + 1) * 32 + px];
        float py  = offy + (float)(tap / 3) + (float)(ho - 1);
        float pxf = offx + (float)(tap % 3) + (float)(pxg + px - 1);
        float fy = floorf(py), fx = floorf(pxf);
        int y0 = (int)fy, x0 = (int)fx;
        float wy1 = py - fy, wx1 = pxf - fx;
        float wy0 = 1.f - wy1, wx0 = 1.f - wx1;
        bool y0ok = ((unsigned)y0 < 64u);
        bool x0ok = ((unsigned)x0 < 64u);
        bool y1ok = ((unsigned)(y0 + 1) < 64u);
        bool x1ok = ((unsigned)(x0 + 1) < 64u);
        float w00 = (y0ok && x0ok) ? wy0 * wx0 : 0.f;
        float w01 = (y0ok && x1ok) ? wy0 * wx1 : 0.f;
        float w10 = (y1ok && x0ok) ? wy1 * wx0 : 0.f;
        float w11 = (y1ok && x1ok) ? wy1 * wx1 : 0.f;
        int yc0 = min(max(y0, 0), 63);
        int xc0 = min(max(x0, 0), 63);
        int yc1 = min(max(y0 + 1, 0), 63);
        int xc1 = min(max(x0 + 1, 0), 63);
        union { __half2 h; unsigned u; } c0, c1;
        c0.h = __floats2half2_rn(w00, w01);
        c1.h = __floats2half2_rn(w10, w11);
        uint4 rec;
        rec.x = (unsigned)(yc0 * 64 + xc0)
              | ((unsigned)(xc1 - xc0) << 12)
              | ((unsigned)(yc1 - yc0) << 13);
        rec.y = c0.u;
        rec.z = c1.u;
        rec.w = 0u;
        grecL[tap * GSTR + px] = rec;
    }
    __syncthreads();

    // ================= Phase B: gather + MFMA ============================
    floatx4 acc0 = {0.f, 0.f, 0.f, 0.f};
    floatx4 acc1 = {0.f, 0.f, 0.f, 0.f};

    auto gather = [&](int tap) {
        uint4 rec = grecL[tap * GSTR + gpx];
        unsigned a00 = (rec.x & 0xfffu) * 128u + (unsigned)oct * 16u;
        unsigned dx128  = ((rec.x >> 12) & 1u) * 128u;
        unsigned dy8192 = ((rec.x >> 13) & 1u) * 8192u;
        unsigned a01 = a00 + dx128;
        unsigned a10 = a00 + dy8192;
        unsigned a11 = a10 + dx128;
        H8 v00, v01, v10, v11;
        v00.v = *(const half8*)(xpb + a00);
        v01.v = *(const half8*)(xpb + a01);
        v10.v = *(const half8*)(xpb + a10);
        v11.v = *(const half8*)(xpb + a11);
        union { unsigned u; __half2 h; } cy, cz;
        cy.u = rec.y; cz.u = rec.z;
        __half2 W00 = __half2half2(__low2half(cy.h));
        __half2 W01 = __half2half2(__high2half(cy.h));
        __half2 W10 = __half2half2(__low2half(cz.h));
        __half2 W11 = __half2half2(__high2half(cz.h));
        H8 res;
#pragma unroll
        for (int c = 0; c < 4; ++c) {
            __half2 aa = __hmul2(v00.h2[c], W00);
            aa = __hfma2(v01.h2[c], W01, aa);
            aa = __hfma2(v10.h2[c], W10, aa);
            aa = __hfma2(v11.h2[c], W11, aa);
            res.h2[c] = aa;
        }
        *(half8*)&colsT[tap & 1][gpx * CPAD + oct * 8] = res.v;
    };

    gather(0);
    __syncthreads();
#pragma unroll
    for (int tap = 0; tap < 9; ++tap) {
        if (tap < 8) gather(tap + 1);
#pragma unroll
        for (int g = 0; g < 2; ++g) {
            half8 af = *(const half8*)&w2t[(size_t)(tap * 2 + g) * 2048
                                           + (wid * 16 + r) * 32 + q * 8];
            half8 b0 = *(const half8*)&colsT[tap & 1][r * CPAD + g * 32 + q * 8];
            half8 b1 = *(const half8*)&colsT[tap & 1][(16 + r) * CPAD + g * 32 + q * 8];
            acc0 = __builtin_amdgcn_mfma_f32_16x16x32_f16(af, b0, acc0, 0, 0, 0);
            acc1 = __builtin_amdgcn_mfma_f32_16x16x32_f16(af, b1, acc1, 0, 0, 0);
        }
        if (tap < 8) __syncthreads();
    }

    // ================= epilogue ==========================================
#pragma unroll
    for (int reg = 0; reg < 4; ++reg) {
        int co = wid * 16 + q * 4 + reg;
        float bias = b_dcn[co];
        size_t o = (((size_t)b * 64 + co) * 64 + ho) * 64 + pxg;
        out[o + r]      = acc0[reg] + bias;
        out[o + 16 + r] = acc1[reg] + bias;
    }
}

// ---------------------------------------------------------------------------
// Fallback: R11's proven fused kernel (weights straight from global),
// used only if ws is too small for the NHWC copy.
#define FCPAD 40
__launch_bounds__(256, 4)
__global__ void dcn_fb(const float* __restrict__ x,
                       const float* __restrict__ w_dcn,
                       const float* __restrict__ w_off,
                       const float* __restrict__ b_off,
                       const float* __restrict__ b_dcn,
                       float* __restrict__ out) {
    const int bid = blockIdx.x;
    const int s   = bid >> 3;
    const int b   = ((bid & 7) << 1) | (s >> 7);
    const int ho  = (s >> 1) & 63;
    const int hlf = s & 1;
    const int t    = threadIdx.x;
    const int lane = t & 63;
    const int wid  = __builtin_amdgcn_readfirstlane(t >> 6);
    const int r    = lane & 15;
    const int q    = lane >> 4;
    const int px   = t & 31;
    const int kq   = t >> 5;

    __shared__ __align__(16) _Float16 colsT[2][32 * FCPAD];
    __shared__ __align__(16) float    offlds[KOFF * 32];

    const float* xb = x + (size_t)b * 64 * 4096;
    const int pxg = hlf * 32;

    {
        floatx4 am = {0.f, 0.f, 0.f, 0.f};
        const int m = wid & 1, n = wid >> 1;
        auto stageA = [&](int i) {
            const int tap = i >> 1;
            const int dy = tap / 3, dxk = tap - dy * 3;
            const int y  = ho + dy - 1;
            const int xc = pxg + px + dxk - 1;
            const bool ok = ((unsigned)y < 64u) && ((unsigned)xc < 64u);
            const float* xp = xb + ((size_t)((i & 1) * 32 + kq * 4)) * 4096
                                 + y * 64 + xc;
            float va[4];
#pragma unroll
            for (int j = 0; j < 4; ++j) va[j] = ok ? xp[(size_t)j * 4096] : 0.f;
#pragma unroll
            for (int j = 0; j < 4; ++j)
                colsT[i & 1][px * FCPAD + kq * 4 + j] = (_Float16)va[j];
        };
        auto loadA = [&](int i) -> half8 {
            const int tap = i >> 1;
            const int cin0 = (i & 1) * 32 + q * 8;
            const int co = m * 16 + r;
            half8 v;
#pragma unroll
            for (int j = 0; j < 8; ++j)
                v[j] = (co < KOFF) ? (_Float16)w_off[co * 576 + (cin0 + j) * 9 + tap]
                                   : (_Float16)0.f;
            return v;
        };
        stageA(0);
        __syncthreads();
#pragma unroll
        for (int i = 0; i < 18; ++i) {
            if (i < 17) stageA(i + 1);
            half8 a = loadA(i);
            half8 bfr = *(const half8*)&colsT[i & 1][(n * 16 + r) * FCPAD + q * 8];
            am = __builtin_amdgcn_mfma_f32_16x16x32_f16(a, bfr, am, 0, 0, 0);
            __syncthreads();
        }
#pragma unroll
        for (int reg = 0; reg < 4; ++reg) {
            int co = m * 16 + q * 4 + reg;
            if (co < KOFF)
                offlds[co * 32 + (n * 16 + r)] = am[reg] + b_off[co];
        }
    }
    __syncthreads();

    unsigned rmeta[9], rw0[9], rw1[9];
#pragma unroll
    for (int tap = 0; tap < 9; ++tap) {
        float offy = offlds[(2 * tap) * 32 + px];
        float offx = offlds[(2 * tap + 1) * 32 + px];
        float py  = offy + (float)(tap / 3) + (float)(ho - 1);
        float pxf = offx + (float)(tap % 3) + (float)(pxg + px - 1);
        float fy = floorf(py), fx = floorf(pxf);
        int y0 = (int)fy, x0 = (int)fx;
        float wy1 = py - fy, wx1 = pxf - fx;
        float wy0 = 1.f - wy1, wx0 = 1.f - wx1;
        bool y0ok = ((unsigned)y0 < 64u);
        bool x0ok = ((unsigned)x0 < 64u);
        bool y1ok = ((unsigned)(y0 + 1) < 64u);
        bool x1ok = ((unsigned)(x0 + 1) < 64u);
        float w00 = (y0ok && x0ok) ? wy0 * wx0 : 0.f;
        float w01 = (y0ok && x1ok) ? wy0 * wx1 : 0.f;
        float w10 = (y1ok && x0ok) ? wy1 * wx0 : 0.f;
        float w11 = (y1ok && x1ok) ? wy1 * wx1 : 0.f;
        int yc0 = min(max(y0, 0), 63);
        int xc0 = min(max(x0, 0), 63);
        int yc1 = min(max(y0 + 1, 0), 63);
        int xc1 = min(max(x0 + 1, 0), 63);
        union { __half2 h; unsigned u; } c0, c1;
        c0.h = __floats2half2_rn(w00, w01);
        c1.h = __floats2half2_rn(w10, w11);
        rmeta[tap] = (unsigned)(yc0 * 64 + xc0)
                   | ((unsigned)(xc1 - xc0) << 12)
                   | ((unsigned)(yc1 - yc0) << 13);
        rw0[tap] = c0.u;
        rw1[tap] = c1.u;
    }

    floatx4 acc0 = {0.f, 0.f, 0.f, 0.f};
    floatx4 acc1 = {0.f, 0.f, 0.f, 0.f};

    auto gather = [&](int i) {
        const int tap = i >> 1;
        const unsigned m = rmeta[tap];
        const unsigned a00 = (m & 0xfffu) << 2;
        const unsigned a01 = a00 + ((m >> 10) & 4u);
        const unsigned a10 = a00 + ((m >> 5) & 256u);
        const unsigned a11 = a10 + ((m >> 10) & 4u);
        const char* base = (const char*)xb
                         + ((size_t)((i & 1) * 32 + kq * 4)) * 16384;
        float v00[4], v01[4], v10[4], v11[4];
#pragma unroll
        for (int j = 0; j < 4; ++j) {
            const char* xp = base + (size_t)j * 16384;
            v00[j] = *(const float*)(xp + a00);
            v01[j] = *(const float*)(xp + a01);
            v10[j] = *(const float*)(xp + a10);
            v11[j] = *(const float*)(xp + a11);
        }
        union { unsigned u; __half2 h; } c0, c1;
        c0.u = rw0[tap]; c1.u = rw1[tap];
        const float wA = __half2float(c0.h.x), wB = __half2float(c0.h.y);
        const float wC = __half2float(c1.h.x), wD = __half2float(c1.h.y);
#pragma unroll
        for (int j = 0; j < 4; ++j)
            colsT[i & 1][px * FCPAD + kq * 4 + j] =
                (_Float16)(v00[j] * wA + v01[j] * wB + v10[j] * wC + v11[j] * wD);
    };

    auto load_af = [&](int i) -> half8 {
        const int tap = i >> 1;
        const int cin0 = (i & 1) * 32 + q * 8;
        half8 v;
#pragma unroll
        for (int j = 0; j < 8; ++j)
            v[j] = (_Float16)w_dcn[(wid * 16 + r) * 576 + (cin0 + j) * 9 + tap];
        return v;
    };

    gather(0);
    __syncthreads();
#pragma unroll
    for (int i = 0; i < 18; ++i) {
        if (i < 17) gather(i + 1);
        half8 af = load_af(i);
        half8 b0 = *(const half8*)&colsT[i & 1][r * FCPAD + q * 8];
        half8 b1 = *(const half8*)&colsT[i & 1][(16 + r) * FCPAD + q * 8];
        acc0 = __builtin_amdgcn_mfma_f32_16x16x32_f16(af, b0, acc0, 0, 0, 0);
        acc1 = __builtin_amdgcn_mfma_f32_16x16x32_f16(af, b1, acc1, 0, 0, 0);
        if (i < 17) __syncthreads();
    }

#pragma unroll
    for (int reg = 0; reg < 4; ++reg) {
        int co = wid * 16 + q * 4 + reg;
        float bias = b_dcn[co];
        size_t o = (((size_t)b * 64 + co) * 64 + ho) * 64 + pxg;
        out[o + r]      = acc0[reg] + bias;
        out[o + 16 + r] = acc1[reg] + bias;
    }
}

// ---------------------------------------------------------------------------
extern "C" void kernel_launch(void* const* d_in, const int* in_sizes, int n_in,
                              void* d_out, int out_size, void* d_ws, size_t ws_size,
                              hipStream_t stream) {
    const float* x     = (const float*)d_in[0];
    const float* w_off = (const float*)d_in[1];
    const float* b_off = (const float*)d_in[2];
    const float* w_dcn = (const float*)d_in[3];
    const float* b_dcn = (const float*)d_in[4];
    float* out = (float*)d_out;

    char* ws = (char*)d_ws;
    _Float16* w2t    = (_Float16*)ws;
    _Float16* woff2t = (_Float16*)(ws + WOFF2T_OFF);
    _Float16* xh     = (_Float16*)(ws + X_OFF);

    if (ws_size >= (size_t)WS_NEED) {
        prep<<<16384, 256, 0, stream>>>(x, w_dcn, w_off, w2t, woff2t, xh);
        dcn_main<<<2048, 256, 0, stream>>>(xh, w2t, woff2t, b_off, b_dcn, out);
    } else {
        dcn_fb<<<2048, 256, 0, stream>>>(x, w_dcn, w_off, b_off, b_dcn, out);
    }
}

// Round 13
// 110.155 us; speedup vs baseline: 2.1648x; 1.1213x over previous
//
#include <hip/hip_runtime.h>
#include <hip/hip_fp16.h>

// DeformConv2d: B=16, Cin=64, Cout=64, H=W=64, K=3, stride=1, pad=1, dil=1
// Round 13:
//  prep: LDS-tiled NCHW->NHWC f16 transpose, fully coalesced both sides
//    (R12 scattered 2B/lane writes at 128B stride).
//  dcn_main: phase A/B restructured issue-loads -> MFMA(tap) ->
//    wait+combine+store(tap+1) -> barrier, hiding gather latency behind
//    the MFMA+ds_read block. Weight frags prefetched one tap ahead.

#define KOFF 18
#define CPAD 72            // halfs per px row in colsT (64 cin + 8 pad)
#define GSTR 33            // LDS geometry record stride (uint4)

#define W2T_HALFS    (18 * 64 * 32)     // [i][64co][32kl], k' = tap*64+cin
#define WOFF2T_HALFS (18 * 32 * 32)     // [i][32co][32kl]
#define W2T_BYTES    (W2T_HALFS * 2)    // 73728
#define WOFF2T_OFF   W2T_BYTES
#define X_OFF        (W2T_BYTES + WOFF2T_HALFS * 2)   // 110592 (16B aligned)
#define XH_BYTES     (16 * 64 * 64 * 64 * 2)          // 8388608
#define WS_NEED      (X_OFF + XH_BYTES)               // 8499200

typedef _Float16 half8 __attribute__((ext_vector_type(8)));
typedef float floatx4 __attribute__((ext_vector_type(4)));

union H8 { half8 v; __half2 h2[4]; uint4 u; };

// ---------------------------------------------------------------------------
// prep: blocks [0,1024): LDS-tiled transpose of one (b,y) plane.
//       blocks [1024,1240): weight repack (tap-major f16).
__global__ void prep(const float* __restrict__ x,
                     const float* __restrict__ w_dcn,
                     const float* __restrict__ w_off,
                     _Float16* __restrict__ w2t,
                     _Float16* __restrict__ woff2t,
                     _Float16* __restrict__ xh) {
    const int bi = blockIdx.x;
    const int t  = threadIdx.x;
    if (bi < 1024) {
        const int b = bi >> 6, y = bi & 63;
        __shared__ __align__(16) _Float16 tile[64 * CPAD];   // [xx][cin+pad]
        const int xx = t & 63;
        const int c4 = t >> 6;            // 4 cin rows per pass
        const float* xp = x + (((size_t)b * 64) * 64 + y) * 64;
#pragma unroll
        for (int p = 0; p < 16; ++p) {
            int cin = p * 4 + c4;
            tile[xx * CPAD + cin] = (_Float16)xp[(size_t)cin * 4096 + xx];
        }
        __syncthreads();
        const int oct = t & 7;
        const int xl  = t >> 3;           // 0..31
        _Float16* op = xh + ((((size_t)b * 64 + y) * 64) << 6);
#pragma unroll
        for (int p = 0; p < 2; ++p) {
            int xr = p * 32 + xl;
            half8 v = *(const half8*)&tile[xr * CPAD + oct * 8];
            *(half8*)&op[(size_t)xr * 64 + oct * 8] = v;
        }
    } else {
        int e = (bi - 1024) * 256 + t;    // 0..55295
        if (e < W2T_HALFS) {
            int kl = e & 31, co = (e >> 5) & 63, i = e >> 11;
            int tap = i >> 1, cin = (i & 1) * 32 + kl;
            w2t[e] = (_Float16)w_dcn[co * 576 + cin * 9 + tap];
        } else {
            int e2 = e - W2T_HALFS;
            int kl = e2 & 31, co = (e2 >> 5) & 31, i = e2 >> 10;
            int tap = i >> 1, cin = (i & 1) * 32 + kl;
            woff2t[e2] = (co < KOFF) ? (_Float16)w_off[co * 576 + cin * 9 + tap]
                                     : (_Float16)0.f;
        }
    }
}

// ---------------------------------------------------------------------------
__launch_bounds__(256, 4)
__global__ void dcn_main(const _Float16* __restrict__ xh,
                         const _Float16* __restrict__ w2t,
                         const _Float16* __restrict__ woff2t,
                         const float* __restrict__ b_off,
                         const float* __restrict__ b_dcn,
                         float* __restrict__ out) {
    const int bid = blockIdx.x;                 // 0..2047
    const int s   = bid >> 3;
    const int b   = ((bid & 7) << 1) | (s >> 7);
    const int ho  = (s >> 1) & 63;
    const int hlf = s & 1;
    const int t    = threadIdx.x;
    const int lane = t & 63;
    const int wid  = __builtin_amdgcn_readfirstlane(t >> 6);
    const int r    = lane & 15;
    const int q    = lane >> 4;
    const int gpx  = t >> 3;                    // 0..31 gather/stage pixel
    const int oct  = t & 7;                     // 8-cin octet
    const int pxg  = hlf * 32;

    __shared__ __align__(16) _Float16 colsT[2][32 * CPAD];  // 9216 B
    __shared__ __align__(16) float    offlds[KOFF * 32];    // 2304 B
    __shared__ __align__(16) uint4    grecL[9 * GSTR];      // 4752 B

    const _Float16* xb = xh + ((size_t)b << 18);
    const char* xpb = (const char*)xb;

    // ================= Phase A: offset conv via MFMA =====================
    {
        floatx4 am = {0.f, 0.f, 0.f, 0.f};
        const int m = wid & 1, n = wid >> 1;

        auto loadS = [&](int tap) -> half8 {
            const int dy = tap / 3, dxk = tap - dy * 3;
            const int y  = ho + dy - 1;
            const int xc = pxg + gpx + dxk - 1;
            half8 v = {};
            if (((unsigned)y < 64u) && ((unsigned)xc < 64u))
                v = *(const half8*)&xb[(((size_t)y * 64 + xc) << 6) + oct * 8];
            return v;
        };
        auto loadWA = [&](int tap, int g) -> half8 {
            return *(const half8*)&woff2t[(tap * 2 + g) * 1024
                                          + (m * 16 + r) * 32 + q * 8];
        };

        half8 sv = loadS(0);
        *(half8*)&colsT[0][gpx * CPAD + oct * 8] = sv;
        half8 a0 = loadWA(0, 0), a1 = loadWA(0, 1);
        __syncthreads();
#pragma unroll
        for (int tap = 0; tap < 9; ++tap) {
            half8 sn, a0n, a1n;
            if (tap < 8) {
                sn  = loadS(tap + 1);          // issue vmem early
                a0n = loadWA(tap + 1, 0);
                a1n = loadWA(tap + 1, 1);
            }
            half8 bf0 = *(const half8*)&colsT[tap & 1][(n * 16 + r) * CPAD + q * 8];
            half8 bf1 = *(const half8*)&colsT[tap & 1][(n * 16 + r) * CPAD + 32 + q * 8];
            am = __builtin_amdgcn_mfma_f32_16x16x32_f16(a0, bf0, am, 0, 0, 0);
            am = __builtin_amdgcn_mfma_f32_16x16x32_f16(a1, bf1, am, 0, 0, 0);
            if (tap < 8) {
                *(half8*)&colsT[(tap + 1) & 1][gpx * CPAD + oct * 8] = sn;
                a0 = a0n; a1 = a1n;
            }
            __syncthreads();
        }
#pragma unroll
        for (int reg = 0; reg < 4; ++reg) {
            int co = m * 16 + q * 4 + reg;
            if (co < KOFF)
                offlds[co * 32 + n * 16 + r] = am[reg] + b_off[co];
        }
    }
    __syncthreads();

    // ================= Geometry records (R9-proven encoding) =============
    for (int e = t; e < 9 * 32; e += 256) {
        int tap = e >> 5, px = e & 31;
        float offy = offlds[(2 * tap) * 32 + px];
        float offx = offlds[(2 * tap + 1) * 32 + px];
        float py  = offy + (float)(tap / 3) + (float)(ho - 1);
        float pxf = offx + (float)(tap % 3) + (float)(pxg + px - 1);
        float fy = floorf(py), fx = floorf(pxf);
        int y0 = (int)fy, x0 = (int)fx;
        float wy1 = py - fy, wx1 = pxf - fx;
        float wy0 = 1.f - wy1, wx0 = 1.f - wx1;
        bool y0ok = ((unsigned)y0 < 64u);
        bool x0ok = ((unsigned)x0 < 64u);
        bool y1ok = ((unsigned)(y0 + 1) < 64u);
        bool x1ok = ((unsigned)(x0 + 1) < 64u);
        float w00 = (y0ok && x0ok) ? wy0 * wx0 : 0.f;
        float w01 = (y0ok && x1ok) ? wy0 * wx1 : 0.f;
        float w10 = (y1ok && x0ok) ? wy1 * wx0 : 0.f;
        float w11 = (y1ok && x1ok) ? wy1 * wx1 : 0.f;
        int yc0 = min(max(y0, 0), 63);
        int xc0 = min(max(x0, 0), 63);
        int yc1 = min(max(y0 + 1, 0), 63);
        int xc1 = min(max(x0 + 1, 0), 63);
        union { __half2 h; unsigned u; } c0, c1;
        c0.h = __floats2half2_rn(w00, w01);
        c1.h = __floats2half2_rn(w10, w11);
        uint4 rec;
        rec.x = (unsigned)(yc0 * 64 + xc0)
              | ((unsigned)(xc1 - xc0) << 12)
              | ((unsigned)(yc1 - yc0) << 13);
        rec.y = c0.u;
        rec.z = c1.u;
        rec.w = 0u;
        grecL[tap * GSTR + px] = rec;
    }
    __syncthreads();

    // ================= Phase B: gather + MFMA ============================
    floatx4 acc0 = {0.f, 0.f, 0.f, 0.f};
    floatx4 acc1 = {0.f, 0.f, 0.f, 0.f};

    struct G { H8 a, c, d, e; unsigned wy, wz; };

    auto loadB = [&](int tap) -> G {
        uint4 rec = grecL[tap * GSTR + gpx];
        unsigned a00 = (rec.x & 0xfffu) * 128u + (unsigned)oct * 16u;
        unsigned dx128  = ((rec.x >> 12) & 1u) * 128u;
        unsigned dy8192 = ((rec.x >> 13) & 1u) * 8192u;
        G g;
        g.a.v = *(const half8*)(xpb + a00);
        g.c.v = *(const half8*)(xpb + a00 + dx128);
        g.d.v = *(const half8*)(xpb + a00 + dy8192);
        g.e.v = *(const half8*)(xpb + a00 + dy8192 + dx128);
        g.wy = rec.y; g.wz = rec.z;
        return g;
    };
    auto storeB = [&](int tap, G& g) {
        union { unsigned u; __half2 h; } cy, cz;
        cy.u = g.wy; cz.u = g.wz;
        __half2 W00 = __half2half2(__low2half(cy.h));
        __half2 W01 = __half2half2(__high2half(cy.h));
        __half2 W10 = __half2half2(__low2half(cz.h));
        __half2 W11 = __half2half2(__high2half(cz.h));
        H8 res;
#pragma unroll
        for (int c = 0; c < 4; ++c) {
            __half2 aa = __hmul2(g.a.h2[c], W00);
            aa = __hfma2(g.c.h2[c], W01, aa);
            aa = __hfma2(g.d.h2[c], W10, aa);
            aa = __hfma2(g.e.h2[c], W11, aa);
            res.h2[c] = aa;
        }
        *(half8*)&colsT[tap & 1][gpx * CPAD + oct * 8] = res.v;
    };
    auto loadW = [&](int tap, int g) -> half8 {
        return *(const half8*)&w2t[(size_t)(tap * 2 + g) * 2048
                                   + (wid * 16 + r) * 32 + q * 8];
    };

    {
        G g0 = loadB(0);
        storeB(0, g0);
    }
    half8 af0 = loadW(0, 0), af1 = loadW(0, 1);
    __syncthreads();
#pragma unroll
    for (int tap = 0; tap < 9; ++tap) {
        G gn;
        half8 af0n, af1n;
        if (tap < 8) {
            gn   = loadB(tap + 1);             // issue vmem early
            af0n = loadW(tap + 1, 0);
            af1n = loadW(tap + 1, 1);
        }
        // MFMA block for this tap (ds_read + mfma, no dependence on gn)
        half8 b00 = *(const half8*)&colsT[tap & 1][r * CPAD + q * 8];
        half8 b10 = *(const half8*)&colsT[tap & 1][(16 + r) * CPAD + q * 8];
        half8 b01 = *(const half8*)&colsT[tap & 1][r * CPAD + 32 + q * 8];
        half8 b11 = *(const half8*)&colsT[tap & 1][(16 + r) * CPAD + 32 + q * 8];
        acc0 = __builtin_amdgcn_mfma_f32_16x16x32_f16(af0, b00, acc0, 0, 0, 0);
        acc1 = __builtin_amdgcn_mfma_f32_16x16x32_f16(af0, b10, acc1, 0, 0, 0);
        acc0 = __builtin_amdgcn_mfma_f32_16x16x32_f16(af1, b01, acc0, 0, 0, 0);
        acc1 = __builtin_amdgcn_mfma_f32_16x16x32_f16(af1, b11, acc1, 0, 0, 0);
        if (tap < 8) {
            storeB(tap + 1, gn);               // waits vmcnt AFTER the MFMAs
            af0 = af0n; af1 = af1n;
            __syncthreads();
        }
    }

    // ================= epilogue ==========================================
#pragma unroll
    for (int reg = 0; reg < 4; ++reg) {
        int co = wid * 16 + q * 4 + reg;
        float bias = b_dcn[co];
        size_t o = (((size_t)b * 64 + co) * 64 + ho) * 64 + pxg;
        out[o + r]      = acc0[reg] + bias;
        out[o + 16 + r] = acc1[reg] + bias;
    }
}

// ---------------------------------------------------------------------------
// Fallback (R11-proven) used only if ws is too small for the NHWC copy.
#define FCPAD 40
__launch_bounds__(256, 4)
__global__ void dcn_fb(const float* __restrict__ x,
                       const float* __restrict__ w_dcn,
                       const float* __restrict__ w_off,
                       const float* __restrict__ b_off,
                       const float* __restrict__ b_dcn,
                       float* __restrict__ out) {
    const int bid = blockIdx.x;
    const int s   = bid >> 3;
    const int b   = ((bid & 7) << 1) | (s >> 7);
    const int ho  = (s >> 1) & 63;
    const int hlf = s & 1;
    const int t    = threadIdx.x;
    const int lane = t & 63;
    const int wid  = __builtin_amdgcn_readfirstlane(t >> 6);
    const int r    = lane & 15;
    const int q    = lane >> 4;
    const int px   = t & 31;
    const int kq   = t >> 5;

    __shared__ __align__(16) _Float16 colsT[2][32 * FCPAD];
    __shared__ __align__(16) float    offlds[KOFF * 32];

    const float* xb = x + (size_t)b * 64 * 4096;
    const int pxg = hlf * 32;

    {
        floatx4 am = {0.f, 0.f, 0.f, 0.f};
        const int m = wid & 1, n = wid >> 1;
        auto stageA = [&](int i) {
            const int tap = i >> 1;
            const int dy = tap / 3, dxk = tap - dy * 3;
            const int y  = ho + dy - 1;
            const int xc = pxg + px + dxk - 1;
            const bool ok = ((unsigned)y < 64u) && ((unsigned)xc < 64u);
            const float* xp = xb + ((size_t)((i & 1) * 32 + kq * 4)) * 4096
                                 + y * 64 + xc;
            float va[4];
#pragma unroll
            for (int j = 0; j < 4; ++j) va[j] = ok ? xp[(size_t)j * 4096] : 0.f;
#pragma unroll
            for (int j = 0; j < 4; ++j)
                colsT[i & 1][px * FCPAD + kq * 4 + j] = (_Float16)va[j];
        };
        auto loadA = [&](int i) -> half8 {
            const int tap = i >> 1;
            const int cin0 = (i & 1) * 32 + q * 8;
            const int co = m * 16 + r;
            half8 v;
#pragma unroll
            for (int j = 0; j < 8; ++j)
                v[j] = (co < KOFF) ? (_Float16)w_off[co * 576 + (cin0 + j) * 9 + tap]
                                   : (_Float16)0.f;
            return v;
        };
        stageA(0);
        __syncthreads();
#pragma unroll
        for (int i = 0; i < 18; ++i) {
            if (i < 17) stageA(i + 1);
            half8 a = loadA(i);
            half8 bfr = *(const half8*)&colsT[i & 1][(n * 16 + r) * FCPAD + q * 8];
            am = __builtin_amdgcn_mfma_f32_16x16x32_f16(a, bfr, am, 0, 0, 0);
            __syncthreads();
        }
#pragma unroll
        for (int reg = 0; reg < 4; ++reg) {
            int co = m * 16 + q * 4 + reg;
            if (co < KOFF)
                offlds[co * 32 + (n * 16 + r)] = am[reg] + b_off[co];
        }
    }
    __syncthreads();

    unsigned rmeta[9], rw0[9], rw1[9];
#pragma unroll
    for (int tap = 0; tap < 9; ++tap) {
        float offy = offlds[(2 * tap) * 32 + px];
        float offx = offlds[(2 * tap + 1) * 32 + px];
        float py  = offy + (float)(tap / 3) + (float)(ho - 1);
        float pxf = offx + (float)(tap % 3) + (float)(pxg + px - 1);
        float fy = floorf(py), fx = floorf(pxf);
        int y0 = (int)fy, x0 = (int)fx;
        float wy1 = py - fy, wx1 = pxf - fx;
        float wy0 = 1.f - wy1, wx0 = 1.f - wx1;
        bool y0ok = ((unsigned)y0 < 64u);
        bool x0ok = ((unsigned)x0 < 64u);
        bool y1ok = ((unsigned)(y0 + 1) < 64u);
        bool x1ok = ((unsigned)(x0 + 1) < 64u);
        float w00 = (y0ok && x0ok) ? wy0 * wx0 : 0.f;
        float w01 = (y0ok && x1ok) ? wy0 * wx1 : 0.f;
        float w10 = (y1ok && x0ok) ? wy1 * wx0 : 0.f;
        float w11 = (y1ok && x1ok) ? wy1 * wx1 : 0.f;
        int yc0 = min(max(y0, 0), 63);
        int xc0 = min(max(x0, 0), 63);
        int yc1 = min(max(y0 + 1, 0), 63);
        int xc1 = min(max(x0 + 1, 0), 63);
        union { __half2 h; unsigned u; } c0, c1;
        c0.h = __floats2half2_rn(w00, w01);
        c1.h = __floats2half2_rn(w10, w11);
        rmeta[tap] = (unsigned)(yc0 * 64 + xc0)
                   | ((unsigned)(xc1 - xc0) << 12)
                   | ((unsigned)(yc1 - yc0) << 13);
        rw0[tap] = c0.u;
        rw1[tap] = c1.u;
    }

    floatx4 acc0 = {0.f, 0.f, 0.f, 0.f};
    floatx4 acc1 = {0.f, 0.f, 0.f, 0.f};

    auto gather = [&](int i) {
        const int tap = i >> 1;
        const unsigned m = rmeta[tap];
        const unsigned a00 = (m & 0xfffu) << 2;
        const unsigned a01 = a00 + ((m >> 10) & 4u);
        const unsigned a10 = a00 + ((m >> 5) & 256u);
        const unsigned a11 = a10 + ((m >> 10) & 4u);
        const char* base = (const char*)xb
                         + ((size_t)((i & 1) * 32 + kq * 4)) * 16384;
        float v00[4], v01[4], v10[4], v11[4];
#pragma unroll
        for (int j = 0; j < 4; ++j) {
            const char* xp = base + (size_t)j * 16384;
            v00[j] = *(const float*)(xp + a00);
            v01[j] = *(const float*)(xp + a01);
            v10[j] = *(const float*)(xp + a10);
            v11[j] = *(const float*)(xp + a11);
        }
        union { unsigned u; __half2 h; } c0, c1;
        c0.u = rw0[tap]; c1.u = rw1[tap];
        const float wA = __half2float(c0.h.x), wB = __half2float(c0.h.y);
        const float wC = __half2float(c1.h.x), wD = __half2float(c1.h.y);
#pragma unroll
        for (int j = 0; j < 4; ++j)
            colsT[i & 1][px * FCPAD + kq * 4 + j] =
                (_Float16)(v00[j] * wA + v01[j] * wB + v10[j] * wC + v11[j] * wD);
    };

    auto load_af = [&](int i) -> half8 {
        const int tap = i >> 1;
        const int cin0 = (i & 1) * 32 + q * 8;
        half8 v;
#pragma unroll
        for (int j = 0; j < 8; ++j)
            v[j] = (_Float16)w_dcn[(wid * 16 + r) * 576 + (cin0 + j) * 9 + tap];
        return v;
    };

    gather(0);
    __syncthreads();
#pragma unroll
    for (int i = 0; i < 18; ++i) {
        if (i < 17) gather(i + 1);
        half8 af = load_af(i);
        half8 b0 = *(const half8*)&colsT[i & 1][r * FCPAD + q * 8];
        half8 b1 = *(const half8*)&colsT[i & 1][(16 + r) * FCPAD + q * 8];
        acc0 = __builtin_amdgcn_mfma_f32_16x16x32_f16(af, b0, acc0, 0, 0, 0);
        acc1 = __builtin_amdgcn_mfma_f32_16x16x32_f16(af, b1, acc1, 0, 0, 0);
        if (i < 17) __syncthreads();
    }

#pragma unroll
    for (int reg = 0; reg < 4; ++reg) {
        int co = wid * 16 + q * 4 + reg;
        float bias = b_dcn[co];
        size_t o = (((size_t)b * 64 + co) * 64 + ho) * 64 + pxg;
        out[o + r]      = acc0[reg] + bias;
        out[o + 16 + r] = acc1[reg] + bias;
    }
}

// ---------------------------------------------------------------------------
extern "C" void kernel_launch(void* const* d_in, const int* in_sizes, int n_in,
                              void* d_out, int out_size, void* d_ws, size_t ws_size,
                              hipStream_t stream) {
    const float* x     = (const float*)d_in[0];
    const float* w_off = (const float*)d_in[1];
    const float* b_off = (const float*)d_in[2];
    const float* w_dcn = (const float*)d_in[3];
    const float* b_dcn = (const float*)d_in[4];
    float* out = (float*)d_out;

    char* ws = (char*)d_ws;
    _Float16* w2t    = (_Float16*)ws;
    _Float16* woff2t = (_Float16*)(ws + WOFF2T_OFF);
    _Float16* xh     = (_Float16*)(ws + X_OFF);

    if (ws_size >= (size_t)WS_NEED) {
        prep<<<1240, 256, 0, stream>>>(x, w_dcn, w_off, w2t, woff2t, xh);
        dcn_main<<<2048, 256, 0, stream>>>(xh, w2t, woff2t, b_off, b_dcn, out);
    } else {
        dcn_fb<<<2048, 256, 0, stream>>>(x, w_dcn, w_off, b_off, b_dcn, out);
    }
}

// Round 14
// 108.580 us; speedup vs baseline: 2.1962x; 1.0145x over previous
//
#include <hip/hip_runtime.h>
#include <hip/hip_fp16.h>

// DeformConv2d: B=16, Cin=64, Cout=64, H=W=64, K=3, stride=1, pad=1, dil=1
// Round 14: barrier-drain reduction. R13 was barrier-bound (19 syncs/block
// vs pipe-sum ~22us << 45us measured). Taps processed in PAIRS: K=128 per
// barrier, 8 gather + 4 weight loads batched per drain. Barriers 19 -> ~12.
// colsT = 2 x [32px][136] (2 taps per buffer), 24.4 KB LDS.

#define KOFF 18
#define CTS  136           // colsT stride in halfs (2*64 cin + 8 pad)
#define GSTR 33            // LDS geometry record stride (uint4)

#define W2T_HALFS    (18 * 64 * 32)     // [i][64co][32kl], k' = tap*64+cin
#define WOFF2T_HALFS (18 * 32 * 32)     // [i][32co][32kl]
#define W2T_BYTES    (W2T_HALFS * 2)    // 73728
#define WOFF2T_OFF   W2T_BYTES
#define X_OFF        (W2T_BYTES + WOFF2T_HALFS * 2)   // 110592 (16B aligned)
#define XH_BYTES     (16 * 64 * 64 * 64 * 2)          // 8388608
#define WS_NEED      (X_OFF + XH_BYTES)               // 8499200

typedef _Float16 half8 __attribute__((ext_vector_type(8)));
typedef float floatx4 __attribute__((ext_vector_type(4)));

union H8 { half8 v; __half2 h2[4]; uint4 u; };

// ---------------------------------------------------------------------------
// prep: blocks [0,1024): LDS-tiled transpose of one (b,y) plane (coalesced
// both sides). blocks [1024,1240): weight repack (tap-major f16).
__global__ void prep(const float* __restrict__ x,
                     const float* __restrict__ w_dcn,
                     const float* __restrict__ w_off,
                     _Float16* __restrict__ w2t,
                     _Float16* __restrict__ woff2t,
                     _Float16* __restrict__ xh) {
    const int bi = blockIdx.x;
    const int t  = threadIdx.x;
    if (bi < 1024) {
        const int b = bi >> 6, y = bi & 63;
        __shared__ __align__(16) _Float16 tile[64 * 72];
        const int xx = t & 63;
        const int c4 = t >> 6;
        const float* xp = x + (((size_t)b * 64) * 64 + y) * 64;
#pragma unroll
        for (int p = 0; p < 16; ++p) {
            int cin = p * 4 + c4;
            tile[xx * 72 + cin] = (_Float16)xp[(size_t)cin * 4096 + xx];
        }
        __syncthreads();
        const int oct = t & 7;
        const int xl  = t >> 3;
        _Float16* op = xh + ((((size_t)b * 64 + y) * 64) << 6);
#pragma unroll
        for (int p = 0; p < 2; ++p) {
            int xr = p * 32 + xl;
            half8 v = *(const half8*)&tile[xr * 72 + oct * 8];
            *(half8*)&op[(size_t)xr * 64 + oct * 8] = v;
        }
    } else {
        int e = (bi - 1024) * 256 + t;
        if (e < W2T_HALFS) {
            int kl = e & 31, co = (e >> 5) & 63, i = e >> 11;
            int tap = i >> 1, cin = (i & 1) * 32 + kl;
            w2t[e] = (_Float16)w_dcn[co * 576 + cin * 9 + tap];
        } else {
            int e2 = e - W2T_HALFS;
            int kl = e2 & 31, co = (e2 >> 5) & 31, i = e2 >> 10;
            int tap = i >> 1, cin = (i & 1) * 32 + kl;
            woff2t[e2] = (co < KOFF) ? (_Float16)w_off[co * 576 + cin * 9 + tap]
                                     : (_Float16)0.f;
        }
    }
}

// ---------------------------------------------------------------------------
__launch_bounds__(256, 4)
__global__ void dcn_main(const _Float16* __restrict__ xh,
                         const _Float16* __restrict__ w2t,
                         const _Float16* __restrict__ woff2t,
                         const float* __restrict__ b_off,
                         const float* __restrict__ b_dcn,
                         float* __restrict__ out) {
    const int bid = blockIdx.x;                 // 0..2047
    const int s   = bid >> 3;
    const int b   = ((bid & 7) << 1) | (s >> 7);
    const int ho  = (s >> 1) & 63;
    const int hlf = s & 1;
    const int t    = threadIdx.x;
    const int lane = t & 63;
    const int wid  = __builtin_amdgcn_readfirstlane(t >> 6);
    const int r    = lane & 15;
    const int q    = lane >> 4;
    const int gpx  = t >> 3;                    // 0..31 gather/stage pixel
    const int oct  = t & 7;                     // 8-cin octet
    const int pxg  = hlf * 32;

    __shared__ __align__(16) _Float16 colsT[2][32 * CTS];   // 17408 B
    __shared__ __align__(16) float    offlds[KOFF * 32];    // 2304 B
    __shared__ __align__(16) uint4    grecL[9 * GSTR];      // 4752 B

    const _Float16* xb = xh + ((size_t)b << 18);
    const char* xpb = (const char*)xb;

    // ================= Phase A: offset conv via MFMA (tap pairs) =========
    {
        floatx4 am = {0.f, 0.f, 0.f, 0.f};
        const int m = wid & 1, n = wid >> 1;

        auto loadS = [&](int tap) -> half8 {
            const int dy = tap / 3, dxk = tap - dy * 3;
            const int y  = ho + dy - 1;
            const int xc = pxg + gpx + dxk - 1;
            half8 v = {};
            if (((unsigned)y < 64u) && ((unsigned)xc < 64u))
                v = *(const half8*)&xb[(((size_t)y * 64 + xc) << 6) + oct * 8];
            return v;
        };
        auto loadWA = [&](int i) -> half8 {
            return *(const half8*)&woff2t[i * 1024 + (m * 16 + r) * 32 + q * 8];
        };

        {
            half8 s0 = loadS(0), s1 = loadS(1);
            *(half8*)&colsT[0][gpx * CTS + oct * 8]      = s0;
            *(half8*)&colsT[0][gpx * CTS + 64 + oct * 8] = s1;
        }
        __syncthreads();
#pragma unroll
        for (int p = 0; p < 5; ++p) {
            half8 sn0, sn1;
            if (p < 4) {
                sn0 = loadS(2 * p + 2);
                if (p < 3) sn1 = loadS(2 * p + 3);
            }
            const int nkg = (p < 4) ? 4 : 2;
#pragma unroll
            for (int kg = 0; kg < 4; ++kg) {
                if (kg < nkg) {
                    half8 a  = loadWA(4 * p + kg);
                    half8 bf = *(const half8*)&colsT[p & 1][(n * 16 + r) * CTS
                                                            + kg * 32 + q * 8];
                    am = __builtin_amdgcn_mfma_f32_16x16x32_f16(a, bf, am, 0, 0, 0);
                }
            }
            if (p < 4) {
                *(half8*)&colsT[(p + 1) & 1][gpx * CTS + oct * 8] = sn0;
                if (p < 3)
                    *(half8*)&colsT[(p + 1) & 1][gpx * CTS + 64 + oct * 8] = sn1;
                __syncthreads();
            }
        }
#pragma unroll
        for (int reg = 0; reg < 4; ++reg) {
            int co = m * 16 + q * 4 + reg;
            if (co < KOFF)
                offlds[co * 32 + n * 16 + r] = am[reg] + b_off[co];
        }
    }
    __syncthreads();

    // ================= Geometry records (R9-proven encoding) =============
    for (int e = t; e < 9 * 32; e += 256) {
        int tap = e >> 5, px = e & 31;
        float offy = offlds[(2 * tap) * 32 + px];
        float offx = offlds[(2 * tap + 1) * 32 + px];
        float py  = offy + (float)(tap / 3) + (float)(ho - 1);
        float pxf = offx + (float)(tap % 3) + (float)(pxg + px - 1);
        float fy = floorf(py), fx = floorf(pxf);
        int y0 = (int)fy, x0 = (int)fx;
        float wy1 = py - fy, wx1 = pxf - fx;
        float wy0 = 1.f - wy1, wx0 = 1.f - wx1;
        bool y0ok = ((unsigned)y0 < 64u);
        bool x0ok = ((unsigned)x0 < 64u);
        bool y1ok = ((unsigned)(y0 + 1) < 64u);
        bool x1ok = ((unsigned)(x0 + 1) < 64u);
        float w00 = (y0ok && x0ok) ? wy0 * wx0 : 0.f;
        float w01 = (y0ok && x1ok) ? wy0 * wx1 : 0.f;
        float w10 = (y1ok && x0ok) ? wy1 * wx0 : 0.f;
        float w11 = (y1ok && x1ok) ? wy1 * wx1 : 0.f;
        int yc0 = min(max(y0, 0), 63);
        int xc0 = min(max(x0, 0), 63);
        int yc1 = min(max(y0 + 1, 0), 63);
        int xc1 = min(max(x0 + 1, 0), 63);
        union { __half2 h; unsigned u; } c0, c1;
        c0.h = __floats2half2_rn(w00, w01);
        c1.h = __floats2half2_rn(w10, w11);
        uint4 rec;
        rec.x = (unsigned)(yc0 * 64 + xc0)
              | ((unsigned)(xc1 - xc0) << 12)
              | ((unsigned)(yc1 - yc0) << 13);
        rec.y = c0.u;
        rec.z = c1.u;
        rec.w = 0u;
        grecL[tap * GSTR + px] = rec;
    }
    __syncthreads();

    // ================= Phase B: gather + MFMA (tap pairs) ================
    floatx4 acc0 = {0.f, 0.f, 0.f, 0.f};
    floatx4 acc1 = {0.f, 0.f, 0.f, 0.f};

    struct GP { H8 v[8]; unsigned wy0, wz0, wy1, wz1; };

    auto loadPairB = [&](int p) -> GP {
        GP g;
#pragma unroll
        for (int l = 0; l < 2; ++l) {
            int tap = 2 * p + l;
            if (tap < 9) {
                uint4 rec = grecL[tap * GSTR + gpx];
                unsigned a00 = (rec.x & 0xfffu) * 128u + (unsigned)oct * 16u;
                unsigned dx128  = ((rec.x >> 12) & 1u) * 128u;
                unsigned dy8192 = ((rec.x >> 13) & 1u) * 8192u;
                g.v[4 * l + 0].v = *(const half8*)(xpb + a00);
                g.v[4 * l + 1].v = *(const half8*)(xpb + a00 + dx128);
                g.v[4 * l + 2].v = *(const half8*)(xpb + a00 + dy8192);
                g.v[4 * l + 3].v = *(const half8*)(xpb + a00 + dy8192 + dx128);
                if (l == 0) { g.wy0 = rec.y; g.wz0 = rec.z; }
                else        { g.wy1 = rec.y; g.wz1 = rec.z; }
            }
        }
        return g;
    };
    auto storePairB = [&](int p, int buf, GP& g) {
#pragma unroll
        for (int l = 0; l < 2; ++l) {
            int tap = 2 * p + l;
            if (tap < 9) {
                union { unsigned u; __half2 h; } cy, cz;
                cy.u = l ? g.wy1 : g.wy0;
                cz.u = l ? g.wz1 : g.wz0;
                __half2 W00 = __half2half2(__low2half(cy.h));
                __half2 W01 = __half2half2(__high2half(cy.h));
                __half2 W10 = __half2half2(__low2half(cz.h));
                __half2 W11 = __half2half2(__high2half(cz.h));
                H8 res;
#pragma unroll
                for (int c = 0; c < 4; ++c) {
                    __half2 aa = __hmul2(g.v[4 * l + 0].h2[c], W00);
                    aa = __hfma2(g.v[4 * l + 1].h2[c], W01, aa);
                    aa = __hfma2(g.v[4 * l + 2].h2[c], W10, aa);
                    aa = __hfma2(g.v[4 * l + 3].h2[c], W11, aa);
                    res.h2[c] = aa;
                }
                *(half8*)&colsT[buf][gpx * CTS + l * 64 + oct * 8] = res.v;
            }
        }
    };
    auto loadW = [&](int i) -> half8 {
        return *(const half8*)&w2t[(size_t)i * 2048 + (wid * 16 + r) * 32 + q * 8];
    };

    {
        GP g0 = loadPairB(0);
        storePairB(0, 0, g0);
    }
    half8 wf[4];
#pragma unroll
    for (int kg = 0; kg < 4; ++kg) wf[kg] = loadW(kg);
    __syncthreads();

#pragma unroll
    for (int p = 0; p < 5; ++p) {
        GP gn;
        half8 wfn[4];
        if (p < 4) {
            gn = loadPairB(p + 1);
#pragma unroll
            for (int kg = 0; kg < 4; ++kg)
                if (4 * (p + 1) + kg < 18) wfn[kg] = loadW(4 * (p + 1) + kg);
        }
        const int nkg = (p < 4) ? 4 : 2;
#pragma unroll
        for (int kg = 0; kg < 4; ++kg) {
            if (kg < nkg) {
                half8 b0 = *(const half8*)&colsT[p & 1][r * CTS + kg * 32 + q * 8];
                half8 b1 = *(const half8*)&colsT[p & 1][(16 + r) * CTS + kg * 32 + q * 8];
                acc0 = __builtin_amdgcn_mfma_f32_16x16x32_f16(wf[kg], b0, acc0, 0, 0, 0);
                acc1 = __builtin_amdgcn_mfma_f32_16x16x32_f16(wf[kg], b1, acc1, 0, 0, 0);
            }
        }
        if (p < 4) {
            storePairB(p + 1, (p + 1) & 1, gn);   // vmcnt waits AFTER the MFMAs
#pragma unroll
            for (int kg = 0; kg < 4; ++kg) wf[kg] = wfn[kg];
            __syncthreads();
        }
    }

    // ================= epilogue ==========================================
#pragma unroll
    for (int reg = 0; reg < 4; ++reg) {
        int co = wid * 16 + q * 4 + reg;
        float bias = b_dcn[co];
        size_t o = (((size_t)b * 64 + co) * 64 + ho) * 64 + pxg;
        out[o + r]      = acc0[reg] + bias;
        out[o + 16 + r] = acc1[reg] + bias;
    }
}

// ---------------------------------------------------------------------------
// Fallback (R11-proven, x f32 direct) used only if ws too small.
#define FCPAD 40
__launch_bounds__(256, 4)
__global__ void dcn_fb(const float* __restrict__ x,
                       const float* __restrict__ w_dcn,
                       const float* __restrict__ w_off,
                       const float* __restrict__ b_off,
                       const float* __restrict__ b_dcn,
                       float* __restrict__ out) {
    const int bid = blockIdx.x;
    const int s   = bid >> 3;
    const int b   = ((bid & 7) << 1) | (s >> 7);
    const int ho  = (s >> 1) & 63;
    const int hlf = s & 1;
    const int t    = threadIdx.x;
    const int lane = t & 63;
    const int wid  = __builtin_amdgcn_readfirstlane(t >> 6);
    const int r    = lane & 15;
    const int q    = lane >> 4;
    const int px   = t & 31;
    const int kq   = t >> 5;

    __shared__ __align__(16) _Float16 colsT[2][32 * FCPAD];
    __shared__ __align__(16) float    offlds[KOFF * 32];

    const float* xb = x + (size_t)b * 64 * 4096;
    const int pxg = hlf * 32;

    {
        floatx4 am = {0.f, 0.f, 0.f, 0.f};
        const int m = wid & 1, n = wid >> 1;
        auto stageA = [&](int i) {
            const int tap = i >> 1;
            const int dy = tap / 3, dxk = tap - dy * 3;
            const int y  = ho + dy - 1;
            const int xc = pxg + px + dxk - 1;
            const bool ok = ((unsigned)y < 64u) && ((unsigned)xc < 64u);
            const float* xp = xb + ((size_t)((i & 1) * 32 + kq * 4)) * 4096
                                 + y * 64 + xc;
            float va[4];
#pragma unroll
            for (int j = 0; j < 4; ++j) va[j] = ok ? xp[(size_t)j * 4096] : 0.f;
#pragma unroll
            for (int j = 0; j < 4; ++j)
                colsT[i & 1][px * FCPAD + kq * 4 + j] = (_Float16)va[j];
        };
        auto loadA = [&](int i) -> half8 {
            const int tap = i >> 1;
            const int cin0 = (i & 1) * 32 + q * 8;
            const int co = m * 16 + r;
            half8 v;
#pragma unroll
            for (int j = 0; j < 8; ++j)
                v[j] = (co < KOFF) ? (_Float16)w_off[co * 576 + (cin0 + j) * 9 + tap]
                                   : (_Float16)0.f;
            return v;
        };
        stageA(0);
        __syncthreads();
#pragma unroll
        for (int i = 0; i < 18; ++i) {
            if (i < 17) stageA(i + 1);
            half8 a = loadA(i);
            half8 bfr = *(const half8*)&colsT[i & 1][(n * 16 + r) * FCPAD + q * 8];
            am = __builtin_amdgcn_mfma_f32_16x16x32_f16(a, bfr, am, 0, 0, 0);
            __syncthreads();
        }
#pragma unroll
        for (int reg = 0; reg < 4; ++reg) {
            int co = m * 16 + q * 4 + reg;
            if (co < KOFF)
                offlds[co * 32 + (n * 16 + r)] = am[reg] + b_off[co];
        }
    }
    __syncthreads();

    unsigned rmeta[9], rw0[9], rw1[9];
#pragma unroll
    for (int tap = 0; tap < 9; ++tap) {
        float offy = offlds[(2 * tap) * 32 + px];
        float offx = offlds[(2 * tap + 1) * 32 + px];
        float py  = offy + (float)(tap / 3) + (float)(ho - 1);
        float pxf = offx + (float)(tap % 3) + (float)(pxg + px - 1);
        float fy = floorf(py), fx = floorf(pxf);
        int y0 = (int)fy, x0 = (int)fx;
        float wy1 = py - fy, wx1 = pxf - fx;
        float wy0 = 1.f - wy1, wx0 = 1.f - wx1;
        bool y0ok = ((unsigned)y0 < 64u);
        bool x0ok = ((unsigned)x0 < 64u);
        bool y1ok = ((unsigned)(y0 + 1) < 64u);
        bool x1ok = ((unsigned)(x0 + 1) < 64u);
        float w00 = (y0ok && x0ok) ? wy0 * wx0 : 0.f;
        float w01 = (y0ok && x1ok) ? wy0 * wx1 : 0.f;
        float w10 = (y1ok && x0ok) ? wy1 * wx0 : 0.f;
        float w11 = (y1ok && x1ok) ? wy1 * wx1 : 0.f;
        int yc0 = min(max(y0, 0), 63);
        int xc0 = min(max(x0, 0), 63);
        int yc1 = min(max(y0 + 1, 0), 63);
        int xc1 = min(max(x0 + 1, 0), 63);
        union { __half2 h; unsigned u; } c0, c1;
        c0.h = __floats2half2_rn(w00, w01);
        c1.h = __floats2half2_rn(w10, w11);
        rmeta[tap] = (unsigned)(yc0 * 64 + xc0)
                   | ((unsigned)(xc1 - xc0) << 12)
                   | ((unsigned)(yc1 - yc0) << 13);
        rw0[tap] = c0.u;
        rw1[tap] = c1.u;
    }

    floatx4 acc0 = {0.f, 0.f, 0.f, 0.f};
    floatx4 acc1 = {0.f, 0.f, 0.f, 0.f};

    auto gather = [&](int i) {
        const int tap = i >> 1;
        const unsigned m = rmeta[tap];
        const unsigned a00 = (m & 0xfffu) << 2;
        const unsigned a01 = a00 + ((m >> 10) & 4u);
        const unsigned a10 = a00 + ((m >> 5) & 256u);
        const unsigned a11 = a10 + ((m >> 10) & 4u);
        const char* base = (const char*)xb
                         + ((size_t)((i & 1) * 32 + kq * 4)) * 16384;
        float v00[4], v01[4], v10[4], v11[4];
#pragma unroll
        for (int j = 0; j < 4; ++j) {
            const char* xp = base + (size_t)j * 16384;
            v00[j] = *(const float*)(xp + a00);
            v01[j] = *(const float*)(xp + a01);
            v10[j] = *(const float*)(xp + a10);
            v11[j] = *(const float*)(xp + a11);
        }
        union { unsigned u; __half2 h; } c0, c1;
        c0.u = rw0[tap]; c1.u = rw1[tap];
        const float wA = __half2float(c0.h.x), wB = __half2float(c0.h.y);
        const float wC = __half2float(c1.h.x), wD = __half2float(c1.h.y);
#pragma unroll
        for (int j = 0; j < 4; ++j)
            colsT[i & 1][px * FCPAD + kq * 4 + j] =
                (_Float16)(v00[j] * wA + v01[j] * wB + v10[j] * wC + v11[j] * wD);
    };

    auto load_af = [&](int i) -> half8 {
        const int tap = i >> 1;
        const int cin0 = (i & 1) * 32 + q * 8;
        half8 v;
#pragma unroll
        for (int j = 0; j < 8; ++j)
            v[j] = (_Float16)w_dcn[(wid * 16 + r) * 576 + (cin0 + j) * 9 + tap];
        return v;
    };

    gather(0);
    __syncthreads();
#pragma unroll
    for (int i = 0; i < 18; ++i) {
        if (i < 17) gather(i + 1);
        half8 af = load_af(i);
        half8 b0 = *(const half8*)&colsT[i & 1][r * FCPAD + q * 8];
        half8 b1 = *(const half8*)&colsT[i & 1][(16 + r) * FCPAD + q * 8];
        acc0 = __builtin_amdgcn_mfma_f32_16x16x32_f16(af, b0, acc0, 0, 0, 0);
        acc1 = __builtin_amdgcn_mfma_f32_16x16x32_f16(af, b1, acc1, 0, 0, 0);
        if (i < 17) __syncthreads();
    }

#pragma unroll
    for (int reg = 0; reg < 4; ++reg) {
        int co = wid * 16 + q * 4 + reg;
        float bias = b_dcn[co];
        size_t o = (((size_t)b * 64 + co) * 64 + ho) * 64 + pxg;
        out[o + r]      = acc0[reg] + bias;
        out[o + 16 + r] = acc1[reg] + bias;
    }
}

// ---------------------------------------------------------------------------
extern "C" void kernel_launch(void* const* d_in, const int* in_sizes, int n_in,
                              void* d_out, int out_size, void* d_ws, size_t ws_size,
                              hipStream_t stream) {
    const float* x     = (const float*)d_in[0];
    const float* w_off = (const float*)d_in[1];
    const float* b_off = (const float*)d_in[2];
    const float* w_dcn = (const float*)d_in[3];
    const float* b_dcn = (const float*)d_in[4];
    float* out = (float*)d_out;

    char* ws = (char*)d_ws;
    _Float16* w2t    = (_Float16*)ws;
    _Float16* woff2t = (_Float16*)(ws + WOFF2T_OFF);
    _Float16* xh     = (_Float16*)(ws + X_OFF);

    if (ws_size >= (size_t)WS_NEED) {
        prep<<<1240, 256, 0, stream>>>(x, w_dcn, w_off, w2t, woff2t, xh);
        dcn_main<<<2048, 256, 0, stream>>>(xh, w2t, woff2t, b_off, b_dcn, out);
    } else {
        dcn_fb<<<2048, 256, 0, stream>>>(x, w_dcn, w_off, b_off, b_dcn, out);
    }
}